// Round 8
// baseline (504.166 us; speedup 1.0000x reference)
//
#include <hip/hip_runtime.h>
#include <hip/hip_bf16.h>

#define NN 20000
#define NE 640000

typedef __attribute__((ext_vector_type(8))) short short8v;   // 8 bf16
typedef __attribute__((ext_vector_type(4))) float float4v;

__device__ __forceinline__ float silu_f(float x) {
    return x / (1.0f + __expf(-x));
}

__device__ __forceinline__ unsigned int f2bf16(float f) {
    __hip_bfloat16 b = __float2bfloat16(f);
    return (unsigned int)*(unsigned short*)&b;
}

// one-instruction bf16-half extraction: v_perm_b32.
// sel 0x01000404 -> {v.b1,v.b0,0,0} = v<<16 (lo short, channel 2p)
// sel 0x03020404 -> {v.b3,v.b2,0,0} = v&0xffff0000 (hi short, channel 2p+1)
#define SEL_LO 0x01000404u
#define SEL_HI 0x03020404u
__device__ __forceinline__ float pickf(unsigned int v, unsigned int sel) {
    return __uint_as_float(__builtin_amdgcn_perm(0u, v, sel));
}

// ---------------------------------------------------------------------------
// Kernel A1 (+ edge histogram folded in): per-node y -> packed bf16,
// R0 plane-major layout [n][plane][16] (144 uints) -- line-optimal for the
// gather (9 x 64B fully-used lines per edge).
// Grid 2500 x 256 = 640000 threads == NE exactly -> histogram rides along.
// ---------------------------------------------------------------------------
__global__ __launch_bounds__(256) void node_y(
    const float* __restrict__ x,
    const float* __restrict__ W10,
    const float* __restrict__ W11,
    const float* __restrict__ W12,
    unsigned int* __restrict__ yAll16,
    const int* __restrict__ ei,
    int* __restrict__ counts)
{
    __shared__ float xs[8][288];
    __shared__ float w10[1024];
    __shared__ float w11[1024];
    __shared__ float w12[1024];
    const int tid = threadIdx.x;
    const int nodeBase = blockIdx.x * 8;

    // folded histogram: one edge per thread
    {
        int e = blockIdx.x * 256 + tid;
        atomicAdd(&counts[ei[NE + e]], 1);
    }

    if (tid < 256) {
        ((float4*)w10)[tid] = ((const float4*)W10)[tid];
        ((float4*)w11)[tid] = ((const float4*)W11)[tid];
        ((float4*)w12)[tid] = ((const float4*)W12)[tid];
    }
    for (int i = tid; i < 576; i += 256) {
        int nl = i / 72, q = i % 72;
        int n = nodeBase + nl;
        float4 v = {0.f, 0.f, 0.f, 0.f};
        if (n < NN) v = ((const float4*)(x + (long)n * 288))[q];
        ((float4*)xs[nl])[q] = v;
    }
    __syncthreads();

    const int nl = tid >> 5, v = tid & 31;
    const int n = nodeBase + nl;
    if (n >= NN) return;

    const float inv_mul = 0.17677669529663687f;  // 1/sqrt(32)
    float vals[9];

    {
        float a = 0.f;
        #pragma unroll
        for (int u = 0; u < 32; ++u) a += xs[nl][u] * w10[u * 32 + v];
        vals[0] = a;
    }
    {
        float a0 = 0.f, a1 = 0.f, a2 = 0.f;
        #pragma unroll
        for (int u = 0; u < 32; ++u) {
            float wv = w11[u * 32 + v];
            a0 += xs[nl][32 + u * 3 + 0] * wv;
            a1 += xs[nl][32 + u * 3 + 1] * wv;
            a2 += xs[nl][32 + u * 3 + 2] * wv;
        }
        vals[1] = a0; vals[2] = a1; vals[3] = a2;
    }
    {
        float a[5] = {0.f, 0.f, 0.f, 0.f, 0.f};
        #pragma unroll
        for (int u = 0; u < 32; ++u) {
            float wv = w12[u * 32 + v];
            #pragma unroll
            for (int m = 0; m < 5; ++m) a[m] += xs[nl][128 + u * 5 + m] * wv;
        }
        #pragma unroll
        for (int m = 0; m < 5; ++m) vals[4 + m] = a[m];
    }

    unsigned int* yrow = yAll16 + (long)n * 144;
    const bool evenLane = ((v & 1) == 0);
    #pragma unroll
    for (int pl = 0; pl < 9; ++pl) {
        float mine  = vals[pl] * inv_mul;
        float other = __shfl_xor(mine, 1);
        if (evenLane)
            yrow[pl * 16 + (v >> 1)] = f2bf16(mine) | (f2bf16(other) << 16);
    }
}

// ---------------------------------------------------------------------------
// Kernel A2: sc GEMM. 64 nodes/block; thread = 8 nodes x 3 cols.
// ---------------------------------------------------------------------------
__global__ __launch_bounds__(256) void node_sc(
    const float* __restrict__ x,
    const float* __restrict__ na,
    const float* __restrict__ scW,
    float* __restrict__ sc)
{
    __shared__ float B[128 * 96];
    __shared__ float x0s[64 * 32];
    __shared__ float nas[64 * 4];
    const int tid = threadIdx.x;
    const int nodeBase = blockIdx.x * 64;

    for (int i = tid; i < 3072; i += 256) {
        int qw = i & 7, rest = i >> 3;
        int t = rest & 3, u = (rest >> 2) & 31, h = rest >> 7;
        float4 v = ((const float4*)scW)[i];
        ((float4*)&B[(u * 4 + t) * 96 + h * 32])[qw] = v;
    }
    for (int i = tid; i < 512; i += 256) {
        int nl = i >> 3, q = i & 7;
        int n = nodeBase + nl;
        float4 v = {0.f, 0.f, 0.f, 0.f};
        if (n < NN) v = ((const float4*)(x + (long)n * 288))[q];
        ((float4*)&x0s[nl * 32])[q] = v;
    }
    for (int i = tid; i < 256; i += 256) {
        int nl = i >> 2, t = i & 3;
        int n = nodeBase + nl;
        nas[i] = (n < NN) ? na[n * 4 + t] : 0.f;
    }
    __syncthreads();

    const int g = tid >> 5, c = tid & 31;
    float nav[8][4];
    #pragma unroll
    for (int j = 0; j < 8; ++j)
        #pragma unroll
        for (int t = 0; t < 4; ++t) nav[j][t] = nas[(g * 8 + j) * 4 + t];

    float acc[3][8];
    #pragma unroll
    for (int cc = 0; cc < 3; ++cc)
        #pragma unroll
        for (int j = 0; j < 8; ++j) acc[cc][j] = 0.f;

    for (int u = 0; u < 32; ++u) {
        float aj[8];
        #pragma unroll
        for (int j = 0; j < 8; ++j) aj[j] = x0s[(g * 8 + j) * 32 + u];
        #pragma unroll
        for (int t = 0; t < 4; ++t) {
            float b0 = B[(u * 4 + t) * 96 + c];
            float b1 = B[(u * 4 + t) * 96 + 32 + c];
            float b2 = B[(u * 4 + t) * 96 + 64 + c];
            #pragma unroll
            for (int j = 0; j < 8; ++j) {
                float p = aj[j] * nav[j][t];
                acc[0][j] += p * b0;
                acc[1][j] += p * b1;
                acc[2][j] += p * b2;
            }
        }
    }

    const float inv_sc = 0.08838834764831845f;  // 1/sqrt(128)
    #pragma unroll
    for (int j = 0; j < 8; ++j) {
        int n = nodeBase + g * 8 + j;
        if (n < NN) {
            #pragma unroll
            for (int cc = 0; cc < 3; ++cc)
                sc[((long)cc * NN + n) * 32 + c] = acc[cc][j] * inv_sc;
        }
    }
}

// ---------------------------------------------------------------------------
// scan (block 0) + prep_frags (blocks 1..6) in one launch.
// counts loads vectorized: 5 x int4.
// ---------------------------------------------------------------------------
__global__ __launch_bounds__(1024) void scan_prep(
    const int* __restrict__ counts, int* __restrict__ offsets,
    const float* __restrict__ Wm1, unsigned int* __restrict__ wm1fg)
{
    if (blockIdx.x > 0) {
        int idx = (blockIdx.x - 1) * 1024 + threadIdx.x;   // 0..6143
        int j = idx & 7, lane = (idx >> 3) & 63, sec = idx >> 9;
        int kh = sec / 6, nt = sec % 6;
        int k = kh * 32 + ((lane >> 4) * 8) + j;
        int n = nt * 16 + (lane & 15);
        unsigned int b = f2bf16(Wm1[k * 96 + n] * 0.125f);
        unsigned int other = (unsigned int)__shfl_xor((int)b, 1);
        if ((idx & 1) == 0) wm1fg[idx >> 1] = b | (other << 16);
        return;
    }

    __shared__ int partial[1024];
    const int t = threadIdx.x;
    const int base = t * 20;          // 1024*20 = 20480 >= NN
    int raw[20];
    #pragma unroll
    for (int j = 0; j < 5; ++j) {
        int4 v = ((const int4*)(counts + base))[j];
        raw[j * 4 + 0] = v.x; raw[j * 4 + 1] = v.y;
        raw[j * 4 + 2] = v.z; raw[j * 4 + 3] = v.w;
    }
    int loc[20];
    int s = 0;
    #pragma unroll
    for (int i = 0; i < 20; ++i) {
        int v = (base + i < NN) ? raw[i] : 0;
        loc[i] = s;
        s += v;
    }
    partial[t] = s;
    __syncthreads();
    for (int off = 1; off < 1024; off <<= 1) {
        int v = (t >= off) ? partial[t - off] : 0;
        __syncthreads();
        partial[t] += v;
        __syncthreads();
    }
    int pre = (t == 0) ? 0 : partial[t - 1];
    #pragma unroll
    for (int i = 0; i < 20; ++i)
        if (base + i <= NN) offsets[base + i] = pre + loc[i];
}

// ---------------------------------------------------------------------------
// scatter: ids (edge id for ee gather), (src,dst) pair, and PRE-SORTED ea
// (12-float padded rows, 3x float4 stores at the sorted position).
// ---------------------------------------------------------------------------
__global__ __launch_bounds__(256) void scatter_ids(
    const int* __restrict__ ei, const float* __restrict__ ea,
    const int* __restrict__ offsets, int* __restrict__ cursor,
    int* __restrict__ sidx, int2* __restrict__ ssd,
    float* __restrict__ easorted)
{
    int e = blockIdx.x * 256 + threadIdx.x;
    if (e < NE) {
        int d = ei[NE + e];
        int s = ei[e];
        int pos = offsets[d] + atomicAdd(&cursor[d], 1);
        sidx[pos] = e;
        ssd[pos] = make_int2(s, d);
        const float* er = ea + (long)e * 9;
        float4 a0 = {er[0], er[1], er[2], er[3]};
        float4 a1 = {er[4], er[5], er[6], er[7]};
        float4 a2 = {er[8], 0.f, 0.f, 0.f};
        float4* dst = (float4*)(easorted + (long)pos * 12);
        dst[0] = a0; dst[1] = a1; dst[2] = a2;
    }
}

// ---------------------------------------------------------------------------
// edge_wg: edge_w (R0-proven phases) + fused consume.
// Phase 3 v2 (R8): thread = (dword p 0..15, slice 0..15 of 4 edges), each
// thread computes BOTH bf16 channels 2p/2p+1 from one dword -> y VMEM
// instruction count halves (lanes u=2p/2p+1 previously loaded the SAME
// dword). All 36 y-dwords + 12 w-dwords of a slice are batch-loaded into
// statically-indexed register arrays BEFORE use -> deep MLP (R7 post-mortem:
// 48 VGPRs serialized the gather; occupancy is LDS-bound so registers are
// free). LDS ~28 KB -> 5 blocks/CU.
// ---------------------------------------------------------------------------
__global__ __launch_bounds__(256) void edge_wg(
    const float* __restrict__ ee,
    const int*   __restrict__ sidx,
    const int2*  __restrict__ ssd,
    const float* __restrict__ easorted,
    const float* __restrict__ Wm0,
    const unsigned int* __restrict__ wm1fg,
    const unsigned int* __restrict__ yAll16,
    float* __restrict__ mid)
{
    __shared__ float ees[64 * 8];                 // [le*8 + k]    2 KB
    __shared__ float wm0s[512];                   // [k*64 + i]    2 KB
    __shared__ unsigned short hsf[8 * 64 * 8];    // A-frags       8 KB
    __shared__ unsigned int wtile[64 * 50];       // D packed   12.5 KB
    __shared__ float easp[64 * 12];               // sorted ea     3 KB
    __shared__ int2 sdsh[64];                     // (src,dst)   0.5 KB

    const int tid = threadIdx.x;
    const long pb = (long)blockIdx.x * 64;        // sorted position base

    for (int i = tid; i < 512; i += 256) wm0s[i] = Wm0[i];
    for (int i = tid; i < 512; i += 256) {
        int le = i >> 3, k = i & 7;
        int e = sidx[pb + le];
        ees[i] = ee[(long)e * 8 + k];
    }
    for (int i = tid; i < 192; i += 256)
        ((float4*)easp)[i] = ((const float4*)(easorted + pb * 12))[i];
    if (tid < 64) sdsh[tid] = ssd[pb + tid];
    __syncthreads();

    // phase 1: h -> A-frag slots (bf16). thread = (edge, quarter). [R0 verbatim]
    {
        const float inv_sqrt8 = 0.35355339059327373f;
        const int e = tid >> 2, i0 = (tid & 3) * 16;
        const int tile = e >> 4, m = e & 15;
        float emb[8];
        #pragma unroll
        for (int k = 0; k < 8; ++k) emb[k] = ees[e * 8 + k];
        #pragma unroll
        for (int i = 0; i < 16; ++i) {
            int k = i0 + i;
            float t = 0.f;
            #pragma unroll
            for (int q = 0; q < 8; ++q) t += emb[q] * wm0s[q * 64 + k];
            int kh = k >> 5, kq = (k >> 3) & 3, j = k & 7;
            int lane = kq * 16 + m;
            hsf[((tile * 2 + kh) * 64 + lane) * 8 + j] =
                (unsigned short)f2bf16(silu_f(t * inv_sqrt8));
        }
    }
    __syncthreads();

    // phase 2: MFMA. wave wv -> edge-tile wv x 6 channel-tiles.
    // B-frags straight from global (12 KB, L2-resident). wtile stride 50.
    {
        unsigned short* wts = (unsigned short*)wtile;
        const unsigned short* wm1f = (const unsigned short*)wm1fg;
        const int wv = tid >> 6, lane = tid & 63;
        const short8v a0 = *(const short8v*)&hsf[((wv * 2 + 0) * 64 + lane) * 8];
        const short8v a1 = *(const short8v*)&hsf[((wv * 2 + 1) * 64 + lane) * 8];
        const int col = lane & 15, rowq = (lane >> 4) * 4;
        #pragma unroll
        for (int nt = 0; nt < 6; ++nt) {
            short8v b0 = *(const short8v*)&wm1f[((0 * 6 + nt) * 64 + lane) * 8];
            short8v b1 = *(const short8v*)&wm1f[((1 * 6 + nt) * 64 + lane) * 8];
            float4v acc = {0.f, 0.f, 0.f, 0.f};
            acc = __builtin_amdgcn_mfma_f32_16x16x32_bf16(a0, b0, acc, 0, 0, 0);
            acc = __builtin_amdgcn_mfma_f32_16x16x32_bf16(a1, b1, acc, 0, 0, 0);
            const int c = nt * 16 + col;
            #pragma unroll
            for (int r = 0; r < 4; ++r)
                wts[(wv * 16 + rowq + r) * 100 + c] = (unsigned short)f2bf16(acc[r]);
        }
    }
    __syncthreads();

    // phase 3 v2: consume. thread = (dword p, slice of 4 edges), both
    // channels per dword; batched loads for MLP; run-accum + atomic flush.
    {
        const int pp = tid & 15, sl = tid >> 4;

        const float invAVG = 0.17677669529663687f;                        // 1/sqrt32
        const float c1     = 0.5773502691896258f * 0.17677669529663687f;  // /sqrt3/sqrt32
        const float c2     = 0.4472135954999579f * 0.17677669529663687f;  // /sqrt5/sqrt32

        // batch-issue: 36 independent y dwords + 12 w dwords + dests
        unsigned int yw[4][9];
        unsigned int wu[4][3];
        int dst4[4];
        #pragma unroll
        for (int k = 0; k < 4; ++k) {
            const int le = sl * 4 + k;
            const int2 sd = sdsh[le];
            dst4[k] = sd.y;
            const unsigned int* yb = yAll16 + (long)sd.x * 144 + pp;
            #pragma unroll
            for (int pl = 0; pl < 9; ++pl) yw[k][pl] = yb[pl * 16];
            const unsigned int* wr = wtile + le * 50 + pp;
            wu[k][0] = wr[0]; wu[k][1] = wr[16]; wu[k][2] = wr[32];
        }

        int curD = -1;
        float a0l = 0.f, a0h = 0.f, a1l = 0.f, a1h = 0.f, a2l = 0.f, a2h = 0.f;
        #pragma unroll
        for (int k = 0; k < 4; ++k) {
            const int le = sl * 4 + k;
            const int d = dst4[k];
            if (d != curD) {
                if (curD >= 0) {
                    float* mr = mid + (long)curD * 96 + 2 * pp;
                    atomicAdd(&mr[0],      a0l * invAVG);
                    atomicAdd(&mr[1],      a0h * invAVG);
                    atomicAdd(&mr[32],     a1l * c1);
                    atomicAdd(&mr[33],     a1h * c1);
                    atomicAdd(&mr[64],     a2l * c2);
                    atomicAdd(&mr[65],     a2h * c2);
                }
                curD = d;
                a0l = 0.f; a0h = 0.f; a1l = 0.f; a1h = 0.f; a2l = 0.f; a2h = 0.f;
            }
            const float* eav = easp + le * 12;
            float4 ev0 = *(const float4*)&eav[0];
            float4 ev1 = *(const float4*)&eav[4];
            float  ev8 = eav[8];

            // lo channel (2p)
            a0l += pickf(wu[k][0], SEL_LO) * pickf(yw[k][0], SEL_LO) * ev0.x;
            float d1l = pickf(yw[k][1], SEL_LO) * ev0.y
                      + pickf(yw[k][2], SEL_LO) * ev0.z
                      + pickf(yw[k][3], SEL_LO) * ev0.w;
            a1l += pickf(wu[k][1], SEL_LO) * d1l;
            float d2l = pickf(yw[k][4], SEL_LO) * ev1.x
                      + pickf(yw[k][5], SEL_LO) * ev1.y
                      + pickf(yw[k][6], SEL_LO) * ev1.z
                      + pickf(yw[k][7], SEL_LO) * ev1.w
                      + pickf(yw[k][8], SEL_LO) * ev8;
            a2l += pickf(wu[k][2], SEL_LO) * d2l;

            // hi channel (2p+1)
            a0h += pickf(wu[k][0], SEL_HI) * pickf(yw[k][0], SEL_HI) * ev0.x;
            float d1h = pickf(yw[k][1], SEL_HI) * ev0.y
                      + pickf(yw[k][2], SEL_HI) * ev0.z
                      + pickf(yw[k][3], SEL_HI) * ev0.w;
            a1h += pickf(wu[k][1], SEL_HI) * d1h;
            float d2h = pickf(yw[k][4], SEL_HI) * ev1.x
                      + pickf(yw[k][5], SEL_HI) * ev1.y
                      + pickf(yw[k][6], SEL_HI) * ev1.z
                      + pickf(yw[k][7], SEL_HI) * ev1.w
                      + pickf(yw[k][8], SEL_HI) * ev8;
            a2h += pickf(wu[k][2], SEL_HI) * d2h;
        }
        if (curD >= 0) {
            float* mr = mid + (long)curD * 96 + 2 * pp;
            atomicAdd(&mr[0],      a0l * invAVG);
            atomicAdd(&mr[1],      a0h * invAVG);
            atomicAdd(&mr[32],     a1l * c1);
            atomicAdd(&mr[33],     a1h * c1);
            atomicAdd(&mr[64],     a2l * c2);
            atomicAdd(&mr[65],     a2h * c2);
        }
    }
}

// ---------------------------------------------------------------------------
// Kernel C: output GEMV + sc + silu. float4 staging.
// ---------------------------------------------------------------------------
__global__ __launch_bounds__(256) void node_out(
    const float* __restrict__ mid,
    const float* __restrict__ sc,
    const float* __restrict__ L0,
    const float* __restrict__ L1,
    const float* __restrict__ L2,
    float* __restrict__ out)
{
    __shared__ float l0[32 * 32];
    __shared__ float l1[64 * 32];
    __shared__ float l2[96 * 32];
    __shared__ float ms[8][96];
    const int tid = threadIdx.x;
    const int nodeBase = blockIdx.x * 8;

    if (tid < 256) ((float4*)l0)[tid] = ((const float4*)L0)[tid];
    for (int i = tid; i < 512; i += 256) ((float4*)l1)[i] = ((const float4*)L1)[i];
    for (int i = tid; i < 768; i += 256) ((float4*)l2)[i] = ((const float4*)L2)[i];
    for (int i = tid; i < 192; i += 256) {
        int nl = i / 24, q = i % 24;
        int n = nodeBase + nl;
        float4 v = {0.f, 0.f, 0.f, 0.f};
        if (n < NN) v = ((const float4*)(mid + (long)n * 96))[q];
        ((float4*)ms[nl])[q] = v;
    }
    __syncthreads();

    const int nl = tid >> 5, wv = tid & 31;
    const int n = nodeBase + nl;
    if (n >= NN) return;

    float a0 = 0.f, a1 = 0.f, a2 = 0.f;
    #pragma unroll
    for (int u = 0; u < 32; ++u) {
        float m = ms[nl][u];
        a0 += m * l0[u * 32 + wv];
        a1 += m * l1[u * 32 + wv];
        a2 += m * l2[u * 32 + wv];
    }
    #pragma unroll
    for (int u = 32; u < 64; ++u) {
        float m = ms[nl][u];
        a1 += m * l1[u * 32 + wv];
        a2 += m * l2[u * 32 + wv];
    }
    #pragma unroll
    for (int u = 64; u < 96; ++u) a2 += ms[nl][u] * l2[u * 32 + wv];

    const float is32 = 0.17677669529663687f;
    const float is64 = 0.125f;
    const float is96 = 0.10206207261596575f;
    const long base = (long)n * 32 + wv;
    out[base]                     = silu_f(a0 * is32 + sc[base]);
    out[(long)NN * 32 + base]     = silu_f(a1 * is64 + sc[(long)NN * 32 + base]);
    out[(long)2 * NN * 32 + base] = silu_f(a2 * is96 + sc[(long)2 * NN * 32 + base]);
}

extern "C" void kernel_launch(void* const* d_in, const int* in_sizes, int n_in,
                              void* d_out, int out_size, void* d_ws, size_t ws_size,
                              hipStream_t stream)
{
    const float* x   = (const float*)d_in[0];
    const float* na  = (const float*)d_in[1];
    const float* ee  = (const float*)d_in[2];
    const float* ea  = (const float*)d_in[3];
    const int*   ei  = (const int*)d_in[4];
    const float* W10 = (const float*)d_in[5];
    const float* W11 = (const float*)d_in[6];
    const float* W12 = (const float*)d_in[7];
    const float* Wm0 = (const float*)d_in[8];
    const float* Wm1 = (const float*)d_in[9];
    const float* L0  = (const float*)d_in[10];
    const float* L1  = (const float*)d_in[11];
    const float* L2  = (const float*)d_in[12];
    const float* scW = (const float*)d_in[13];
    float* out = (float*)d_out;

    unsigned int* yAll16 = (unsigned int*)d_ws;           // NN*144 uints
    float* sc      = (float*)(yAll16 + (size_t)NN * 144); // 3*NN*32 f32
    int*   counts  = (int*)(sc + (size_t)3 * NN * 32);    // NN  (memset block)
    int*   cursor  = counts + NN;                         // NN  (memset block)
    float* mid     = (float*)(cursor + NN);               // NN*96 (memset block)
    int*   offsets = (int*)(mid + (size_t)NN * 96);       // NN+1 (+3 pad)
    int*   sidx    = offsets + NN + 4;                    // NE
    int2*  ssd     = (int2*)(sidx + NE);                  // NE int2 (8B-aligned)
    float* easorted = (float*)(ssd + NE);                 // NE*12 f32 (16B-aligned)
    unsigned int* wm1fg = (unsigned int*)(easorted + (size_t)NE * 12); // 3072

    // zero counts + cursor + mid in one shot (contiguous)
    (void)hipMemsetAsync(counts, 0, (size_t)(2 * NN + NN * 96) * sizeof(int), stream);

    node_y<<<(NN + 7) / 8, 256, 0, stream>>>(x, W10, W11, W12, yAll16, ei, counts);
    scan_prep<<<7, 1024, 0, stream>>>(counts, offsets, Wm1, wm1fg);
    scatter_ids<<<(NE + 255) / 256, 256, 0, stream>>>(ei, ea, offsets, cursor,
                                                      sidx, ssd, easorted);
    node_sc<<<(NN + 63) / 64, 256, 0, stream>>>(x, na, scW, sc);

    edge_wg<<<NE / 64, 256, 0, stream>>>(ee, sidx, ssd, easorted,
                                         Wm0, wm1fg, yAll16, mid);

    node_out<<<(NN + 7) / 8, 256, 0, stream>>>(mid, sc, L0, L1, L2, out);
}

// Round 9
// 357.691 us; speedup vs baseline: 1.4095x; 1.4095x over previous
//
#include <hip/hip_runtime.h>
#include <hip/hip_bf16.h>

#define NN 20000
#define NE 640000

typedef __attribute__((ext_vector_type(8))) short short8v;   // 8 bf16
typedef __attribute__((ext_vector_type(4))) float float4v;
typedef __attribute__((ext_vector_type(4))) unsigned int uint4v;

__device__ __forceinline__ float silu_f(float x) {
    return x / (1.0f + __expf(-x));
}

__device__ __forceinline__ unsigned int f2bf16(float f) {
    __hip_bfloat16 b = __float2bfloat16(f);
    return (unsigned int)*(unsigned short*)&b;
}

__device__ __forceinline__ float bfpick(unsigned int v, bool odd) {
    return odd ? __uint_as_float(v & 0xffff0000u) : __uint_as_float(v << 16);
}

// ---------------------------------------------------------------------------
// Kernel A1 (+ edge histogram folded in): per-node y -> packed bf16,
// R0 plane-major layout [n][plane][16] (144 uints) -- line-optimal for the
// gather (9 x 64B fully-used lines per edge).
// Grid 2500 x 256 = 640000 threads == NE exactly -> histogram rides along.
// ---------------------------------------------------------------------------
__global__ __launch_bounds__(256) void node_y(
    const float* __restrict__ x,
    const float* __restrict__ W10,
    const float* __restrict__ W11,
    const float* __restrict__ W12,
    unsigned int* __restrict__ yAll16,
    const int* __restrict__ ei,
    int* __restrict__ counts)
{
    __shared__ float xs[8][288];
    __shared__ float w10[1024];
    __shared__ float w11[1024];
    __shared__ float w12[1024];
    const int tid = threadIdx.x;
    const int nodeBase = blockIdx.x * 8;

    // folded histogram: one edge per thread
    {
        int e = blockIdx.x * 256 + tid;
        atomicAdd(&counts[ei[NE + e]], 1);
    }

    if (tid < 256) {
        ((float4*)w10)[tid] = ((const float4*)W10)[tid];
        ((float4*)w11)[tid] = ((const float4*)W11)[tid];
        ((float4*)w12)[tid] = ((const float4*)W12)[tid];
    }
    for (int i = tid; i < 576; i += 256) {
        int nl = i / 72, q = i % 72;
        int n = nodeBase + nl;
        float4 v = {0.f, 0.f, 0.f, 0.f};
        if (n < NN) v = ((const float4*)(x + (long)n * 288))[q];
        ((float4*)xs[nl])[q] = v;
    }
    __syncthreads();

    const int nl = tid >> 5, v = tid & 31;
    const int n = nodeBase + nl;
    if (n >= NN) return;

    const float inv_mul = 0.17677669529663687f;  // 1/sqrt(32)
    float vals[9];

    {
        float a = 0.f;
        #pragma unroll
        for (int u = 0; u < 32; ++u) a += xs[nl][u] * w10[u * 32 + v];
        vals[0] = a;
    }
    {
        float a0 = 0.f, a1 = 0.f, a2 = 0.f;
        #pragma unroll
        for (int u = 0; u < 32; ++u) {
            float wv = w11[u * 32 + v];
            a0 += xs[nl][32 + u * 3 + 0] * wv;
            a1 += xs[nl][32 + u * 3 + 1] * wv;
            a2 += xs[nl][32 + u * 3 + 2] * wv;
        }
        vals[1] = a0; vals[2] = a1; vals[3] = a2;
    }
    {
        float a[5] = {0.f, 0.f, 0.f, 0.f, 0.f};
        #pragma unroll
        for (int u = 0; u < 32; ++u) {
            float wv = w12[u * 32 + v];
            #pragma unroll
            for (int m = 0; m < 5; ++m) a[m] += xs[nl][128 + u * 5 + m] * wv;
        }
        #pragma unroll
        for (int m = 0; m < 5; ++m) vals[4 + m] = a[m];
    }

    unsigned int* yrow = yAll16 + (long)n * 144;
    const bool evenLane = ((v & 1) == 0);
    #pragma unroll
    for (int pl = 0; pl < 9; ++pl) {
        float mine  = vals[pl] * inv_mul;
        float other = __shfl_xor(mine, 1);
        if (evenLane)
            yrow[pl * 16 + (v >> 1)] = f2bf16(mine) | (f2bf16(other) << 16);
    }
}

// ---------------------------------------------------------------------------
// Kernel A2: sc GEMM. 64 nodes/block; thread = 8 nodes x 3 cols.
// ---------------------------------------------------------------------------
__global__ __launch_bounds__(256) void node_sc(
    const float* __restrict__ x,
    const float* __restrict__ na,
    const float* __restrict__ scW,
    float* __restrict__ sc)
{
    __shared__ float B[128 * 96];
    __shared__ float x0s[64 * 32];
    __shared__ float nas[64 * 4];
    const int tid = threadIdx.x;
    const int nodeBase = blockIdx.x * 64;

    for (int i = tid; i < 3072; i += 256) {
        int qw = i & 7, rest = i >> 3;
        int t = rest & 3, u = (rest >> 2) & 31, h = rest >> 7;
        float4 v = ((const float4*)scW)[i];
        ((float4*)&B[(u * 4 + t) * 96 + h * 32])[qw] = v;
    }
    for (int i = tid; i < 512; i += 256) {
        int nl = i >> 3, q = i & 7;
        int n = nodeBase + nl;
        float4 v = {0.f, 0.f, 0.f, 0.f};
        if (n < NN) v = ((const float4*)(x + (long)n * 288))[q];
        ((float4*)&x0s[nl * 32])[q] = v;
    }
    for (int i = tid; i < 256; i += 256) {
        int nl = i >> 2, t = i & 3;
        int n = nodeBase + nl;
        nas[i] = (n < NN) ? na[n * 4 + t] : 0.f;
    }
    __syncthreads();

    const int g = tid >> 5, c = tid & 31;
    float nav[8][4];
    #pragma unroll
    for (int j = 0; j < 8; ++j)
        #pragma unroll
        for (int t = 0; t < 4; ++t) nav[j][t] = nas[(g * 8 + j) * 4 + t];

    float acc[3][8];
    #pragma unroll
    for (int cc = 0; cc < 3; ++cc)
        #pragma unroll
        for (int j = 0; j < 8; ++j) acc[cc][j] = 0.f;

    for (int u = 0; u < 32; ++u) {
        float aj[8];
        #pragma unroll
        for (int j = 0; j < 8; ++j) aj[j] = x0s[(g * 8 + j) * 32 + u];
        #pragma unroll
        for (int t = 0; t < 4; ++t) {
            float b0 = B[(u * 4 + t) * 96 + c];
            float b1 = B[(u * 4 + t) * 96 + 32 + c];
            float b2 = B[(u * 4 + t) * 96 + 64 + c];
            #pragma unroll
            for (int j = 0; j < 8; ++j) {
                float p = aj[j] * nav[j][t];
                acc[0][j] += p * b0;
                acc[1][j] += p * b1;
                acc[2][j] += p * b2;
            }
        }
    }

    const float inv_sc = 0.08838834764831845f;  // 1/sqrt(128)
    #pragma unroll
    for (int j = 0; j < 8; ++j) {
        int n = nodeBase + g * 8 + j;
        if (n < NN) {
            #pragma unroll
            for (int cc = 0; cc < 3; ++cc)
                sc[((long)cc * NN + n) * 32 + c] = acc[cc][j] * inv_sc;
        }
    }
}

// ---------------------------------------------------------------------------
// scan (block 0) + prep_frags (blocks 1..6) in one launch.
// counts loads vectorized: 5 x int4.
// ---------------------------------------------------------------------------
__global__ __launch_bounds__(1024) void scan_prep(
    const int* __restrict__ counts, int* __restrict__ offsets,
    const float* __restrict__ Wm1, unsigned int* __restrict__ wm1fg)
{
    if (blockIdx.x > 0) {
        int idx = (blockIdx.x - 1) * 1024 + threadIdx.x;   // 0..6143
        int j = idx & 7, lane = (idx >> 3) & 63, sec = idx >> 9;
        int kh = sec / 6, nt = sec % 6;
        int k = kh * 32 + ((lane >> 4) * 8) + j;
        int n = nt * 16 + (lane & 15);
        unsigned int b = f2bf16(Wm1[k * 96 + n] * 0.125f);
        unsigned int other = (unsigned int)__shfl_xor((int)b, 1);
        if ((idx & 1) == 0) wm1fg[idx >> 1] = b | (other << 16);
        return;
    }

    __shared__ int partial[1024];
    const int t = threadIdx.x;
    const int base = t * 20;          // 1024*20 = 20480 >= NN
    int raw[20];
    #pragma unroll
    for (int j = 0; j < 5; ++j) {
        int4 v = ((const int4*)(counts + base))[j];
        raw[j * 4 + 0] = v.x; raw[j * 4 + 1] = v.y;
        raw[j * 4 + 2] = v.z; raw[j * 4 + 3] = v.w;
    }
    int loc[20];
    int s = 0;
    #pragma unroll
    for (int i = 0; i < 20; ++i) {
        int v = (base + i < NN) ? raw[i] : 0;
        loc[i] = s;
        s += v;
    }
    partial[t] = s;
    __syncthreads();
    for (int off = 1; off < 1024; off <<= 1) {
        int v = (t >= off) ? partial[t - off] : 0;
        __syncthreads();
        partial[t] += v;
        __syncthreads();
    }
    int pre = (t == 0) ? 0 : partial[t - 1];
    #pragma unroll
    for (int i = 0; i < 20; ++i)
        if (base + i <= NN) offsets[base + i] = pre + loc[i];
}

// ---------------------------------------------------------------------------
// scatter: ids (edge id for ee gather), (src,dst) pair, and PRE-SORTED ea
// (12-float padded rows, 3x float4 stores at the sorted position).
// ---------------------------------------------------------------------------
__global__ __launch_bounds__(256) void scatter_ids(
    const int* __restrict__ ei, const float* __restrict__ ea,
    const int* __restrict__ offsets, int* __restrict__ cursor,
    int* __restrict__ sidx, int2* __restrict__ ssd,
    float* __restrict__ easorted)
{
    int e = blockIdx.x * 256 + threadIdx.x;
    if (e < NE) {
        int d = ei[NE + e];
        int s = ei[e];
        int pos = offsets[d] + atomicAdd(&cursor[d], 1);
        sidx[pos] = e;
        ssd[pos] = make_int2(s, d);
        const float* er = ea + (long)e * 9;
        float4 a0 = {er[0], er[1], er[2], er[3]};
        float4 a1 = {er[4], er[5], er[6], er[7]};
        float4 a2 = {er[8], 0.f, 0.f, 0.f};
        float4* dst = (float4*)(easorted + (long)pos * 12);
        dst[0] = a0; dst[1] = a1; dst[2] = a2;
    }
}

// ---------------------------------------------------------------------------
// edge_wg v3 (R9): A-fragments computed DIRECTLY in registers.
// MFMA A-layout: lane l of wave wv owns edge wv*16+(l&15), k=(l>>4)*8+j
// (frag a0) and 32+(l>>4)*8+j (frag a1). Each lane computes exactly its own
// 16 h-values with the R0-identical per-k accumulation order
// (t += emb[q]*wm0s[q*64+k], q=0..7) -> bit-identical wtile, no hsf LDS
// round-trip, one barrier fewer, hsf bank conflicts gone.
// LDS 20.0 KB -> 8 blocks/CU = 32 waves/CU (was 28.7 KB -> 5 blocks, 50%
// occupancy; kernel is gather-latency-bound so waves are the lever).
// Phase 3 = R6-proven verbatim (bfpick, thread=(u, slice of 8), run-accum
// + atomic flush; R7 pickf and R8 batch variants both measured slower).
// ---------------------------------------------------------------------------
__global__ __launch_bounds__(256) void edge_wg(
    const float* __restrict__ ee,
    const int*   __restrict__ sidx,
    const int2*  __restrict__ ssd,
    const float* __restrict__ easorted,
    const float* __restrict__ Wm0,
    const unsigned int* __restrict__ wm1fg,
    const unsigned int* __restrict__ yAll16,
    float* __restrict__ mid)
{
    __shared__ float ees[64 * 8];                 // [le*8 + k]    2 KB
    __shared__ float wm0s[512];                   // [k*64 + i]    2 KB
    __shared__ unsigned int wtile[64 * 50];       // D packed   12.5 KB
    __shared__ float easp[64 * 12];               // sorted ea     3 KB
    __shared__ int2 sdsh[64];                     // (src,dst)   0.5 KB

    const int tid = threadIdx.x;
    const long pb = (long)blockIdx.x * 64;        // sorted position base

    for (int i = tid; i < 512; i += 256) wm0s[i] = Wm0[i];
    for (int i = tid; i < 512; i += 256) {
        int le = i >> 3, k = i & 7;
        int e = sidx[pb + le];
        ees[i] = ee[(long)e * 8 + k];
    }
    for (int i = tid; i < 192; i += 256)
        ((float4*)easp)[i] = ((const float4*)(easorted + pb * 12))[i];
    if (tid < 64) sdsh[tid] = ssd[pb + tid];
    __syncthreads();

    // phase A (merged 1+2): per-lane A-frags in registers, then MFMA.
    {
        const float inv_sqrt8 = 0.35355339059327373f;
        const int wv = tid >> 6, l = tid & 63;
        const int le = wv * 16 + (l & 15);
        const int kb = (l >> 4) * 8;

        float emb[8];
        #pragma unroll
        for (int q = 0; q < 8; ++q) emb[q] = ees[le * 8 + q];

        unsigned int pa0[4], pa1[4];
        #pragma unroll
        for (int i = 0; i < 4; ++i) {
            float h2[2];
            #pragma unroll
            for (int t2 = 0; t2 < 2; ++t2) {
                int k = kb + i * 2 + t2;
                float t = 0.f;
                #pragma unroll
                for (int q = 0; q < 8; ++q) t += emb[q] * wm0s[q * 64 + k];
                h2[t2] = silu_f(t * inv_sqrt8);
            }
            pa0[i] = f2bf16(h2[0]) | (f2bf16(h2[1]) << 16);
        }
        #pragma unroll
        for (int i = 0; i < 4; ++i) {
            float h2[2];
            #pragma unroll
            for (int t2 = 0; t2 < 2; ++t2) {
                int k = 32 + kb + i * 2 + t2;
                float t = 0.f;
                #pragma unroll
                for (int q = 0; q < 8; ++q) t += emb[q] * wm0s[q * 64 + k];
                h2[t2] = silu_f(t * inv_sqrt8);
            }
            pa1[i] = f2bf16(h2[0]) | (f2bf16(h2[1]) << 16);
        }

        uint4v u0 = {pa0[0], pa0[1], pa0[2], pa0[3]};
        uint4v u1 = {pa1[0], pa1[1], pa1[2], pa1[3]};
        const short8v a0f = __builtin_bit_cast(short8v, u0);
        const short8v a1f = __builtin_bit_cast(short8v, u1);

        unsigned short* wts = (unsigned short*)wtile;
        const unsigned short* wm1f = (const unsigned short*)wm1fg;
        const int col = l & 15, rowq = (l >> 4) * 4;
        #pragma unroll
        for (int nt = 0; nt < 6; ++nt) {
            short8v b0 = *(const short8v*)&wm1f[((0 * 6 + nt) * 64 + l) * 8];
            short8v b1 = *(const short8v*)&wm1f[((1 * 6 + nt) * 64 + l) * 8];
            float4v acc = {0.f, 0.f, 0.f, 0.f};
            acc = __builtin_amdgcn_mfma_f32_16x16x32_bf16(a0f, b0, acc, 0, 0, 0);
            acc = __builtin_amdgcn_mfma_f32_16x16x32_bf16(a1f, b1, acc, 0, 0, 0);
            const int c = nt * 16 + col;
            #pragma unroll
            for (int r = 0; r < 4; ++r)
                wts[(wv * 16 + rowq + r) * 100 + c] = (unsigned short)f2bf16(acc[r]);
        }
    }
    __syncthreads();

    // phase 3: consume (R6-proven verbatim). thread = (channel u, slice sl
    // of 8 sorted edges); run-accumulation, atomic flush on dest change.
    {
        const int u = tid & 31, sl = tid >> 5;
        const int p = u >> 1;
        const bool odd = (u & 1);

        const float invAVG = 0.17677669529663687f;                        // 1/sqrt32
        const float c1     = 0.5773502691896258f * 0.17677669529663687f;  // /sqrt3/sqrt32
        const float c2     = 0.4472135954999579f * 0.17677669529663687f;  // /sqrt5/sqrt32

        int curD = -1;
        float a0 = 0.f, a1 = 0.f, a2 = 0.f;
        #pragma unroll
        for (int k = 0; k < 8; ++k) {
            const int le = sl * 8 + k;
            const int2 sd = sdsh[le];
            if (sd.y != curD) {
                if (curD >= 0) {
                    atomicAdd(&mid[(long)curD * 96 + u],      a0 * invAVG);
                    atomicAdd(&mid[(long)curD * 96 + 32 + u], a1 * c1);
                    atomicAdd(&mid[(long)curD * 96 + 64 + u], a2 * c2);
                }
                curD = sd.y; a0 = 0.f; a1 = 0.f; a2 = 0.f;
            }
            const unsigned int* wr = wtile + le * 50;
            const unsigned int* yb = yAll16 + (long)sd.x * 144;
            const float* eav = easp + le * 12;

            float4 ev0 = *(const float4*)&eav[0];
            float4 ev1 = *(const float4*)&eav[4];
            float  ev8 = eav[8];

            float w0 = bfpick(wr[p], odd);
            float w1 = bfpick(wr[16 + p], odd);
            float w2 = bfpick(wr[32 + p], odd);

            a0 += w0 * bfpick(yb[p], odd) * ev0.x;

            float d1 = bfpick(yb[16 + p], odd) * ev0.y
                     + bfpick(yb[32 + p], odd) * ev0.z
                     + bfpick(yb[48 + p], odd) * ev0.w;
            a1 += w1 * d1;

            float d2 = bfpick(yb[64 + p], odd) * ev1.x
                     + bfpick(yb[80 + p], odd) * ev1.y
                     + bfpick(yb[96 + p], odd) * ev1.z
                     + bfpick(yb[112 + p], odd) * ev1.w
                     + bfpick(yb[128 + p], odd) * ev8;
            a2 += w2 * d2;
        }
        if (curD >= 0) {
            atomicAdd(&mid[(long)curD * 96 + u],      a0 * invAVG);
            atomicAdd(&mid[(long)curD * 96 + 32 + u], a1 * c1);
            atomicAdd(&mid[(long)curD * 96 + 64 + u], a2 * c2);
        }
    }
}

// ---------------------------------------------------------------------------
// Kernel C: output GEMV + sc + silu. float4 staging.
// ---------------------------------------------------------------------------
__global__ __launch_bounds__(256) void node_out(
    const float* __restrict__ mid,
    const float* __restrict__ sc,
    const float* __restrict__ L0,
    const float* __restrict__ L1,
    const float* __restrict__ L2,
    float* __restrict__ out)
{
    __shared__ float l0[32 * 32];
    __shared__ float l1[64 * 32];
    __shared__ float l2[96 * 32];
    __shared__ float ms[8][96];
    const int tid = threadIdx.x;
    const int nodeBase = blockIdx.x * 8;

    if (tid < 256) ((float4*)l0)[tid] = ((const float4*)L0)[tid];
    for (int i = tid; i < 512; i += 256) ((float4*)l1)[i] = ((const float4*)L1)[i];
    for (int i = tid; i < 768; i += 256) ((float4*)l2)[i] = ((const float4*)L2)[i];
    for (int i = tid; i < 192; i += 256) {
        int nl = i / 24, q = i % 24;
        int n = nodeBase + nl;
        float4 v = {0.f, 0.f, 0.f, 0.f};
        if (n < NN) v = ((const float4*)(mid + (long)n * 96))[q];
        ((float4*)ms[nl])[q] = v;
    }
    __syncthreads();

    const int nl = tid >> 5, wv = tid & 31;
    const int n = nodeBase + nl;
    if (n >= NN) return;

    float a0 = 0.f, a1 = 0.f, a2 = 0.f;
    #pragma unroll
    for (int u = 0; u < 32; ++u) {
        float m = ms[nl][u];
        a0 += m * l0[u * 32 + wv];
        a1 += m * l1[u * 32 + wv];
        a2 += m * l2[u * 32 + wv];
    }
    #pragma unroll
    for (int u = 32; u < 64; ++u) {
        float m = ms[nl][u];
        a1 += m * l1[u * 32 + wv];
        a2 += m * l2[u * 32 + wv];
    }
    #pragma unroll
    for (int u = 64; u < 96; ++u) a2 += ms[nl][u] * l2[u * 32 + wv];

    const float is32 = 0.17677669529663687f;
    const float is64 = 0.125f;
    const float is96 = 0.10206207261596575f;
    const long base = (long)n * 32 + wv;
    out[base]                     = silu_f(a0 * is32 + sc[base]);
    out[(long)NN * 32 + base]     = silu_f(a1 * is64 + sc[(long)NN * 32 + base]);
    out[(long)2 * NN * 32 + base] = silu_f(a2 * is96 + sc[(long)2 * NN * 32 + base]);
}

extern "C" void kernel_launch(void* const* d_in, const int* in_sizes, int n_in,
                              void* d_out, int out_size, void* d_ws, size_t ws_size,
                              hipStream_t stream)
{
    const float* x   = (const float*)d_in[0];
    const float* na  = (const float*)d_in[1];
    const float* ee  = (const float*)d_in[2];
    const float* ea  = (const float*)d_in[3];
    const int*   ei  = (const int*)d_in[4];
    const float* W10 = (const float*)d_in[5];
    const float* W11 = (const float*)d_in[6];
    const float* W12 = (const float*)d_in[7];
    const float* Wm0 = (const float*)d_in[8];
    const float* Wm1 = (const float*)d_in[9];
    const float* L0  = (const float*)d_in[10];
    const float* L1  = (const float*)d_in[11];
    const float* L2  = (const float*)d_in[12];
    const float* scW = (const float*)d_in[13];
    float* out = (float*)d_out;

    unsigned int* yAll16 = (unsigned int*)d_ws;           // NN*144 uints
    float* sc      = (float*)(yAll16 + (size_t)NN * 144); // 3*NN*32 f32
    int*   counts  = (int*)(sc + (size_t)3 * NN * 32);    // NN  (memset block)
    int*   cursor  = counts + NN;                         // NN  (memset block)
    float* mid     = (float*)(cursor + NN);               // NN*96 (memset block)
    int*   offsets = (int*)(mid + (size_t)NN * 96);       // NN+1 (+3 pad)
    int*   sidx    = offsets + NN + 4;                    // NE
    int2*  ssd     = (int2*)(sidx + NE);                  // NE int2 (8B-aligned)
    float* easorted = (float*)(ssd + NE);                 // NE*12 f32 (16B-aligned)
    unsigned int* wm1fg = (unsigned int*)(easorted + (size_t)NE * 12); // 3072

    // zero counts + cursor + mid in one shot (contiguous)
    (void)hipMemsetAsync(counts, 0, (size_t)(2 * NN + NN * 96) * sizeof(int), stream);

    node_y<<<(NN + 7) / 8, 256, 0, stream>>>(x, W10, W11, W12, yAll16, ei, counts);
    scan_prep<<<7, 1024, 0, stream>>>(counts, offsets, Wm1, wm1fg);
    scatter_ids<<<(NE + 255) / 256, 256, 0, stream>>>(ei, ea, offsets, cursor,
                                                      sidx, ssd, easorted);
    node_sc<<<(NN + 63) / 64, 256, 0, stream>>>(x, na, scW, sc);

    edge_wg<<<NE / 64, 256, 0, stream>>>(ee, sidx, ssd, easorted,
                                         Wm0, wm1fg, yAll16, mid);

    node_out<<<(NN + 7) / 8, 256, 0, stream>>>(mid, sc, L0, L1, L2, out);
}

// Round 11
// 356.383 us; speedup vs baseline: 1.4147x; 1.0037x over previous
//
#include <hip/hip_runtime.h>
#include <hip/hip_bf16.h>

#define NN 20000
#define NE 640000

typedef __attribute__((ext_vector_type(8))) short short8v;   // 8 bf16
typedef __attribute__((ext_vector_type(4))) float float4v;
typedef __attribute__((ext_vector_type(4))) unsigned int uint4v;

__device__ __forceinline__ float silu_f(float x) {
    return x / (1.0f + __expf(-x));
}

__device__ __forceinline__ unsigned int f2bf16(float f) {
    __hip_bfloat16 b = __float2bfloat16(f);
    return (unsigned int)*(unsigned short*)&b;
}

// one-instruction bf16-half extraction: v_perm_b32 with per-lane selector.
// sel 0x01000404 -> bytes {v.b1,v.b0,0,0} = v<<16       (lo short, even u)
// sel 0x03020404 -> bytes {v.b3,v.b2,0,0} = v&0xffff0000 (hi short, odd u)
__device__ __forceinline__ float pickf(unsigned int v, unsigned int sel) {
    return __uint_as_float(__builtin_amdgcn_perm(0u, v, sel));
}

// ---------------------------------------------------------------------------
// Kernel A1 (+ edge histogram folded in): per-node y -> packed bf16,
// R0 plane-major layout [n][plane][16] (144 uints) -- line-optimal for the
// gather (9 x 64B fully-used lines per edge).
// Grid 2500 x 256 = 640000 threads == NE exactly -> histogram rides along.
// ---------------------------------------------------------------------------
__global__ __launch_bounds__(256) void node_y(
    const float* __restrict__ x,
    const float* __restrict__ W10,
    const float* __restrict__ W11,
    const float* __restrict__ W12,
    unsigned int* __restrict__ yAll16,
    const int* __restrict__ ei,
    int* __restrict__ counts)
{
    __shared__ float xs[8][288];
    __shared__ float w10[1024];
    __shared__ float w11[1024];
    __shared__ float w12[1024];
    const int tid = threadIdx.x;
    const int nodeBase = blockIdx.x * 8;

    // folded histogram: one edge per thread
    {
        int e = blockIdx.x * 256 + tid;
        atomicAdd(&counts[ei[NE + e]], 1);
    }

    if (tid < 256) {
        ((float4*)w10)[tid] = ((const float4*)W10)[tid];
        ((float4*)w11)[tid] = ((const float4*)W11)[tid];
        ((float4*)w12)[tid] = ((const float4*)W12)[tid];
    }
    for (int i = tid; i < 576; i += 256) {
        int nl = i / 72, q = i % 72;
        int n = nodeBase + nl;
        float4 v = {0.f, 0.f, 0.f, 0.f};
        if (n < NN) v = ((const float4*)(x + (long)n * 288))[q];
        ((float4*)xs[nl])[q] = v;
    }
    __syncthreads();

    const int nl = tid >> 5, v = tid & 31;
    const int n = nodeBase + nl;
    if (n >= NN) return;

    const float inv_mul = 0.17677669529663687f;  // 1/sqrt(32)
    float vals[9];

    {
        float a = 0.f;
        #pragma unroll
        for (int u = 0; u < 32; ++u) a += xs[nl][u] * w10[u * 32 + v];
        vals[0] = a;
    }
    {
        float a0 = 0.f, a1 = 0.f, a2 = 0.f;
        #pragma unroll
        for (int u = 0; u < 32; ++u) {
            float wv = w11[u * 32 + v];
            a0 += xs[nl][32 + u * 3 + 0] * wv;
            a1 += xs[nl][32 + u * 3 + 1] * wv;
            a2 += xs[nl][32 + u * 3 + 2] * wv;
        }
        vals[1] = a0; vals[2] = a1; vals[3] = a2;
    }
    {
        float a[5] = {0.f, 0.f, 0.f, 0.f, 0.f};
        #pragma unroll
        for (int u = 0; u < 32; ++u) {
            float wv = w12[u * 32 + v];
            #pragma unroll
            for (int m = 0; m < 5; ++m) a[m] += xs[nl][128 + u * 5 + m] * wv;
        }
        #pragma unroll
        for (int m = 0; m < 5; ++m) vals[4 + m] = a[m];
    }

    unsigned int* yrow = yAll16 + (long)n * 144;
    const bool evenLane = ((v & 1) == 0);
    #pragma unroll
    for (int pl = 0; pl < 9; ++pl) {
        float mine  = vals[pl] * inv_mul;
        float other = __shfl_xor(mine, 1);
        if (evenLane)
            yrow[pl * 16 + (v >> 1)] = f2bf16(mine) | (f2bf16(other) << 16);
    }
}

// ---------------------------------------------------------------------------
// Kernel A2: sc GEMM. 64 nodes/block; thread = 8 nodes x 3 cols.
// ---------------------------------------------------------------------------
__global__ __launch_bounds__(256) void node_sc(
    const float* __restrict__ x,
    const float* __restrict__ na,
    const float* __restrict__ scW,
    float* __restrict__ sc)
{
    __shared__ float B[128 * 96];
    __shared__ float x0s[64 * 32];
    __shared__ float nas[64 * 4];
    const int tid = threadIdx.x;
    const int nodeBase = blockIdx.x * 64;

    for (int i = tid; i < 3072; i += 256) {
        int qw = i & 7, rest = i >> 3;
        int t = rest & 3, u = (rest >> 2) & 31, h = rest >> 7;
        float4 v = ((const float4*)scW)[i];
        ((float4*)&B[(u * 4 + t) * 96 + h * 32])[qw] = v;
    }
    for (int i = tid; i < 512; i += 256) {
        int nl = i >> 3, q = i & 7;
        int n = nodeBase + nl;
        float4 v = {0.f, 0.f, 0.f, 0.f};
        if (n < NN) v = ((const float4*)(x + (long)n * 288))[q];
        ((float4*)&x0s[nl * 32])[q] = v;
    }
    for (int i = tid; i < 256; i += 256) {
        int nl = i >> 2, t = i & 3;
        int n = nodeBase + nl;
        nas[i] = (n < NN) ? na[n * 4 + t] : 0.f;
    }
    __syncthreads();

    const int g = tid >> 5, c = tid & 31;
    float nav[8][4];
    #pragma unroll
    for (int j = 0; j < 8; ++j)
        #pragma unroll
        for (int t = 0; t < 4; ++t) nav[j][t] = nas[(g * 8 + j) * 4 + t];

    float acc[3][8];
    #pragma unroll
    for (int cc = 0; cc < 3; ++cc)
        #pragma unroll
        for (int j = 0; j < 8; ++j) acc[cc][j] = 0.f;

    for (int u = 0; u < 32; ++u) {
        float aj[8];
        #pragma unroll
        for (int j = 0; j < 8; ++j) aj[j] = x0s[(g * 8 + j) * 32 + u];
        #pragma unroll
        for (int t = 0; t < 4; ++t) {
            float b0 = B[(u * 4 + t) * 96 + c];
            float b1 = B[(u * 4 + t) * 96 + 32 + c];
            float b2 = B[(u * 4 + t) * 96 + 64 + c];
            #pragma unroll
            for (int j = 0; j < 8; ++j) {
                float p = aj[j] * nav[j][t];
                acc[0][j] += p * b0;
                acc[1][j] += p * b1;
                acc[2][j] += p * b2;
            }
        }
    }

    const float inv_sc = 0.08838834764831845f;  // 1/sqrt(128)
    #pragma unroll
    for (int j = 0; j < 8; ++j) {
        int n = nodeBase + g * 8 + j;
        if (n < NN) {
            #pragma unroll
            for (int cc = 0; cc < 3; ++cc)
                sc[((long)cc * NN + n) * 32 + c] = acc[cc][j] * inv_sc;
        }
    }
}

// ---------------------------------------------------------------------------
// scan (block 0) + prep_frags (blocks 1..6) in one launch.
// counts loads vectorized: 5 x int4.
// ---------------------------------------------------------------------------
__global__ __launch_bounds__(1024) void scan_prep(
    const int* __restrict__ counts, int* __restrict__ offsets,
    const float* __restrict__ Wm1, unsigned int* __restrict__ wm1fg)
{
    if (blockIdx.x > 0) {
        int idx = (blockIdx.x - 1) * 1024 + threadIdx.x;   // 0..6143
        int j = idx & 7, lane = (idx >> 3) & 63, sec = idx >> 9;
        int kh = sec / 6, nt = sec % 6;
        int k = kh * 32 + ((lane >> 4) * 8) + j;
        int n = nt * 16 + (lane & 15);
        unsigned int b = f2bf16(Wm1[k * 96 + n] * 0.125f);
        unsigned int other = (unsigned int)__shfl_xor((int)b, 1);
        if ((idx & 1) == 0) wm1fg[idx >> 1] = b | (other << 16);
        return;
    }

    __shared__ int partial[1024];
    const int t = threadIdx.x;
    const int base = t * 20;          // 1024*20 = 20480 >= NN
    int raw[20];
    #pragma unroll
    for (int j = 0; j < 5; ++j) {
        int4 v = ((const int4*)(counts + base))[j];
        raw[j * 4 + 0] = v.x; raw[j * 4 + 1] = v.y;
        raw[j * 4 + 2] = v.z; raw[j * 4 + 3] = v.w;
    }
    int loc[20];
    int s = 0;
    #pragma unroll
    for (int i = 0; i < 20; ++i) {
        int v = (base + i < NN) ? raw[i] : 0;
        loc[i] = s;
        s += v;
    }
    partial[t] = s;
    __syncthreads();
    for (int off = 1; off < 1024; off <<= 1) {
        int v = (t >= off) ? partial[t - off] : 0;
        __syncthreads();
        partial[t] += v;
        __syncthreads();
    }
    int pre = (t == 0) ? 0 : partial[t - 1];
    #pragma unroll
    for (int i = 0; i < 20; ++i)
        if (base + i <= NN) offsets[base + i] = pre + loc[i];
}

// ---------------------------------------------------------------------------
// scatter: ids (edge id for ee gather), (src,dst) pair, and PRE-SORTED ea
// (12-float padded rows, 3x float4 stores at the sorted position).
// ---------------------------------------------------------------------------
__global__ __launch_bounds__(256) void scatter_ids(
    const int* __restrict__ ei, const float* __restrict__ ea,
    const int* __restrict__ offsets, int* __restrict__ cursor,
    int* __restrict__ sidx, int2* __restrict__ ssd,
    float* __restrict__ easorted)
{
    int e = blockIdx.x * 256 + threadIdx.x;
    if (e < NE) {
        int d = ei[NE + e];
        int s = ei[e];
        int pos = offsets[d] + atomicAdd(&cursor[d], 1);
        sidx[pos] = e;
        ssd[pos] = make_int2(s, d);
        const float* er = ea + (long)e * 9;
        float4 a0 = {er[0], er[1], er[2], er[3]};
        float4 a1 = {er[4], er[5], er[6], er[7]};
        float4 a2 = {er[8], 0.f, 0.f, 0.f};
        float4* dst = (float4*)(easorted + (long)pos * 12);
        dst[0] = a0; dst[1] = a1; dst[2] = a2;
    }
}

// ---------------------------------------------------------------------------
// edge_wg v4 (R10/R11): = R9 (A-frags in registers, 20 KB LDS, 8 blocks/CU)
// with phase 3's bfpick (2-3 VALU: shift/and + cndmask on per-lane parity)
// replaced by one-instruction v_perm_b32 (selector VGPR hoisted).
// R9 counters showed VALUBusy 71% / HBM 32% / conflicts ~0 -> genuinely
// VALU-issue-bound, the regime where the 96 picks/thread (~25-35% of VALU)
// are the critical path. (R7 measured pickf slower, but on the 5-block
// bank-conflicted base where spare VALU was free latency cover.)
// ---------------------------------------------------------------------------
__global__ __launch_bounds__(256) void edge_wg(
    const float* __restrict__ ee,
    const int*   __restrict__ sidx,
    const int2*  __restrict__ ssd,
    const float* __restrict__ easorted,
    const float* __restrict__ Wm0,
    const unsigned int* __restrict__ wm1fg,
    const unsigned int* __restrict__ yAll16,
    float* __restrict__ mid)
{
    __shared__ float ees[64 * 8];                 // [le*8 + k]    2 KB
    __shared__ float wm0s[512];                   // [k*64 + i]    2 KB
    __shared__ unsigned int wtile[64 * 50];       // D packed   12.5 KB
    __shared__ float easp[64 * 12];               // sorted ea     3 KB
    __shared__ int2 sdsh[64];                     // (src,dst)   0.5 KB

    const int tid = threadIdx.x;
    const long pb = (long)blockIdx.x * 64;        // sorted position base

    for (int i = tid; i < 512; i += 256) wm0s[i] = Wm0[i];
    for (int i = tid; i < 512; i += 256) {
        int le = i >> 3, k = i & 7;
        int e = sidx[pb + le];
        ees[i] = ee[(long)e * 8 + k];
    }
    for (int i = tid; i < 192; i += 256)
        ((float4*)easp)[i] = ((const float4*)(easorted + pb * 12))[i];
    if (tid < 64) sdsh[tid] = ssd[pb + tid];
    __syncthreads();

    // phase A (merged 1+2): per-lane A-frags in registers, then MFMA.
    {
        const float inv_sqrt8 = 0.35355339059327373f;
        const int wv = tid >> 6, l = tid & 63;
        const int le = wv * 16 + (l & 15);
        const int kb = (l >> 4) * 8;

        float emb[8];
        #pragma unroll
        for (int q = 0; q < 8; ++q) emb[q] = ees[le * 8 + q];

        unsigned int pa0[4], pa1[4];
        #pragma unroll
        for (int i = 0; i < 4; ++i) {
            float h2[2];
            #pragma unroll
            for (int t2 = 0; t2 < 2; ++t2) {
                int k = kb + i * 2 + t2;
                float t = 0.f;
                #pragma unroll
                for (int q = 0; q < 8; ++q) t += emb[q] * wm0s[q * 64 + k];
                h2[t2] = silu_f(t * inv_sqrt8);
            }
            pa0[i] = f2bf16(h2[0]) | (f2bf16(h2[1]) << 16);
        }
        #pragma unroll
        for (int i = 0; i < 4; ++i) {
            float h2[2];
            #pragma unroll
            for (int t2 = 0; t2 < 2; ++t2) {
                int k = 32 + kb + i * 2 + t2;
                float t = 0.f;
                #pragma unroll
                for (int q = 0; q < 8; ++q) t += emb[q] * wm0s[q * 64 + k];
                h2[t2] = silu_f(t * inv_sqrt8);
            }
            pa1[i] = f2bf16(h2[0]) | (f2bf16(h2[1]) << 16);
        }

        uint4v u0 = {pa0[0], pa0[1], pa0[2], pa0[3]};
        uint4v u1 = {pa1[0], pa1[1], pa1[2], pa1[3]};
        const short8v a0f = __builtin_bit_cast(short8v, u0);
        const short8v a1f = __builtin_bit_cast(short8v, u1);

        unsigned short* wts = (unsigned short*)wtile;
        const unsigned short* wm1f = (const unsigned short*)wm1fg;
        const int col = l & 15, rowq = (l >> 4) * 4;
        #pragma unroll
        for (int nt = 0; nt < 6; ++nt) {
            short8v b0 = *(const short8v*)&wm1f[((0 * 6 + nt) * 64 + l) * 8];
            short8v b1 = *(const short8v*)&wm1f[((1 * 6 + nt) * 64 + l) * 8];
            float4v acc = {0.f, 0.f, 0.f, 0.f};
            acc = __builtin_amdgcn_mfma_f32_16x16x32_bf16(a0f, b0, acc, 0, 0, 0);
            acc = __builtin_amdgcn_mfma_f32_16x16x32_bf16(a1f, b1, acc, 0, 0, 0);
            const int c = nt * 16 + col;
            #pragma unroll
            for (int r = 0; r < 4; ++r)
                wts[(wv * 16 + rowq + r) * 100 + c] = (unsigned short)f2bf16(acc[r]);
        }
    }
    __syncthreads();

    // phase 3: consume (R6 structure; picks via v_perm). thread = (channel
    // u, slice sl of 8 sorted edges); run-accumulation, atomic flush.
    {
        const int u = tid & 31, sl = tid >> 5;
        const int p = u >> 1;
        const unsigned int psel = (u & 1) ? 0x03020404u : 0x01000404u;

        const float invAVG = 0.17677669529663687f;                        // 1/sqrt32
        const float c1     = 0.5773502691896258f * 0.17677669529663687f;  // /sqrt3/sqrt32
        const float c2     = 0.4472135954999579f * 0.17677669529663687f;  // /sqrt5/sqrt32

        int curD = -1;
        float a0 = 0.f, a1 = 0.f, a2 = 0.f;
        #pragma unroll
        for (int k = 0; k < 8; ++k) {
            const int le = sl * 8 + k;
            const int2 sd = sdsh[le];
            if (sd.y != curD) {
                if (curD >= 0) {
                    atomicAdd(&mid[(long)curD * 96 + u],      a0 * invAVG);
                    atomicAdd(&mid[(long)curD * 96 + 32 + u], a1 * c1);
                    atomicAdd(&mid[(long)curD * 96 + 64 + u], a2 * c2);
                }
                curD = sd.y; a0 = 0.f; a1 = 0.f; a2 = 0.f;
            }
            const unsigned int* wr = wtile + le * 50;
            const unsigned int* yb = yAll16 + (long)sd.x * 144;
            const float* eav = easp + le * 12;

            float4 ev0 = *(const float4*)&eav[0];
            float4 ev1 = *(const float4*)&eav[4];
            float  ev8 = eav[8];

            float w0 = pickf(wr[p], psel);
            float w1 = pickf(wr[16 + p], psel);
            float w2 = pickf(wr[32 + p], psel);

            a0 += w0 * pickf(yb[p], psel) * ev0.x;

            float d1 = pickf(yb[16 + p], psel) * ev0.y
                     + pickf(yb[32 + p], psel) * ev0.z
                     + pickf(yb[48 + p], psel) * ev0.w;
            a1 += w1 * d1;

            float d2 = pickf(yb[64 + p], psel) * ev1.x
                     + pickf(yb[80 + p], psel) * ev1.y
                     + pickf(yb[96 + p], psel) * ev1.z
                     + pickf(yb[112 + p], psel) * ev1.w
                     + pickf(yb[128 + p], psel) * ev8;
            a2 += w2 * d2;
        }
        if (curD >= 0) {
            atomicAdd(&mid[(long)curD * 96 + u],      a0 * invAVG);
            atomicAdd(&mid[(long)curD * 96 + 32 + u], a1 * c1);
            atomicAdd(&mid[(long)curD * 96 + 64 + u], a2 * c2);
        }
    }
}

// ---------------------------------------------------------------------------
// Kernel C: output GEMV + sc + silu. float4 staging.
// ---------------------------------------------------------------------------
__global__ __launch_bounds__(256) void node_out(
    const float* __restrict__ mid,
    const float* __restrict__ sc,
    const float* __restrict__ L0,
    const float* __restrict__ L1,
    const float* __restrict__ L2,
    float* __restrict__ out)
{
    __shared__ float l0[32 * 32];
    __shared__ float l1[64 * 32];
    __shared__ float l2[96 * 32];
    __shared__ float ms[8][96];
    const int tid = threadIdx.x;
    const int nodeBase = blockIdx.x * 8;

    if (tid < 256) ((float4*)l0)[tid] = ((const float4*)L0)[tid];
    for (int i = tid; i < 512; i += 256) ((float4*)l1)[i] = ((const float4*)L1)[i];
    for (int i = tid; i < 768; i += 256) ((float4*)l2)[i] = ((const float4*)L2)[i];
    for (int i = tid; i < 192; i += 256) {
        int nl = i / 24, q = i % 24;
        int n = nodeBase + nl;
        float4 v = {0.f, 0.f, 0.f, 0.f};
        if (n < NN) v = ((const float4*)(mid + (long)n * 96))[q];
        ((float4*)ms[nl])[q] = v;
    }
    __syncthreads();

    const int nl = tid >> 5, wv = tid & 31;
    const int n = nodeBase + nl;
    if (n >= NN) return;

    float a0 = 0.f, a1 = 0.f, a2 = 0.f;
    #pragma unroll
    for (int u = 0; u < 32; ++u) {
        float m = ms[nl][u];
        a0 += m * l0[u * 32 + wv];
        a1 += m * l1[u * 32 + wv];
        a2 += m * l2[u * 32 + wv];
    }
    #pragma unroll
    for (int u = 32; u < 64; ++u) {
        float m = ms[nl][u];
        a1 += m * l1[u * 32 + wv];
        a2 += m * l2[u * 32 + wv];
    }
    #pragma unroll
    for (int u = 64; u < 96; ++u) a2 += ms[nl][u] * l2[u * 32 + wv];

    const float is32 = 0.17677669529663687f;
    const float is64 = 0.125f;
    const float is96 = 0.10206207261596575f;
    const long base = (long)n * 32 + wv;
    out[base]                     = silu_f(a0 * is32 + sc[base]);
    out[(long)NN * 32 + base]     = silu_f(a1 * is64 + sc[(long)NN * 32 + base]);
    out[(long)2 * NN * 32 + base] = silu_f(a2 * is96 + sc[(long)2 * NN * 32 + base]);
}

extern "C" void kernel_launch(void* const* d_in, const int* in_sizes, int n_in,
                              void* d_out, int out_size, void* d_ws, size_t ws_size,
                              hipStream_t stream)
{
    const float* x   = (const float*)d_in[0];
    const float* na  = (const float*)d_in[1];
    const float* ee  = (const float*)d_in[2];
    const float* ea  = (const float*)d_in[3];
    const int*   ei  = (const int*)d_in[4];
    const float* W10 = (const float*)d_in[5];
    const float* W11 = (const float*)d_in[6];
    const float* W12 = (const float*)d_in[7];
    const float* Wm0 = (const float*)d_in[8];
    const float* Wm1 = (const float*)d_in[9];
    const float* L0  = (const float*)d_in[10];
    const float* L1  = (const float*)d_in[11];
    const float* L2  = (const float*)d_in[12];
    const float* scW = (const float*)d_in[13];
    float* out = (float*)d_out;

    unsigned int* yAll16 = (unsigned int*)d_ws;           // NN*144 uints
    float* sc      = (float*)(yAll16 + (size_t)NN * 144); // 3*NN*32 f32
    int*   counts  = (int*)(sc + (size_t)3 * NN * 32);    // NN  (memset block)
    int*   cursor  = counts + NN;                         // NN  (memset block)
    float* mid     = (float*)(cursor + NN);               // NN*96 (memset block)
    int*   offsets = (int*)(mid + (size_t)NN * 96);       // NN+1 (+3 pad)
    int*   sidx    = offsets + NN + 4;                    // NE
    int2*  ssd     = (int2*)(sidx + NE);                  // NE int2 (8B-aligned)
    float* easorted = (float*)(ssd + NE);                 // NE*12 f32 (16B-aligned)
    unsigned int* wm1fg = (unsigned int*)(easorted + (size_t)NE * 12); // 3072

    // zero counts + cursor + mid in one shot (contiguous)
    (void)hipMemsetAsync(counts, 0, (size_t)(2 * NN + NN * 96) * sizeof(int), stream);

    node_y<<<(NN + 7) / 8, 256, 0, stream>>>(x, W10, W11, W12, yAll16, ei, counts);
    scan_prep<<<7, 1024, 0, stream>>>(counts, offsets, Wm1, wm1fg);
    scatter_ids<<<(NE + 255) / 256, 256, 0, stream>>>(ei, ea, offsets, cursor,
                                                      sidx, ssd, easorted);
    node_sc<<<(NN + 63) / 64, 256, 0, stream>>>(x, na, scW, sc);

    edge_wg<<<NE / 64, 256, 0, stream>>>(ee, sidx, ssd, easorted,
                                         Wm0, wm1fg, yAll16, mid);

    node_out<<<(NN + 7) / 8, 256, 0, stream>>>(mid, sc, L0, L1, L2, out);
}

// Round 12
// 353.231 us; speedup vs baseline: 1.4273x; 1.0089x over previous
//
#include <hip/hip_runtime.h>
#include <hip/hip_bf16.h>

#define NN 20000
#define NE 640000

typedef __attribute__((ext_vector_type(8))) short short8v;   // 8 bf16
typedef __attribute__((ext_vector_type(4))) float float4v;
typedef __attribute__((ext_vector_type(4))) unsigned int uint4v;

__device__ __forceinline__ float silu_f(float x) {
    return x / (1.0f + __expf(-x));
}

__device__ __forceinline__ unsigned int f2bf16(float f) {
    __hip_bfloat16 b = __float2bfloat16(f);
    return (unsigned int)*(unsigned short*)&b;
}

// one-instruction bf16-half extraction: v_perm_b32 with per-lane selector.
// sel 0x01000404 -> bytes {v.b1,v.b0,0,0} = v<<16       (lo short, even u)
// sel 0x03020404 -> bytes {v.b3,v.b2,0,0} = v&0xffff0000 (hi short, odd u)
__device__ __forceinline__ float pickf(unsigned int v, unsigned int sel) {
    return __uint_as_float(__builtin_amdgcn_perm(0u, v, sel));
}

// ---------------------------------------------------------------------------
// Kernel A1 (+ edge histogram folded in): per-node y -> packed bf16,
// R0 plane-major layout [n][plane][16] (144 uints) -- line-optimal for the
// gather (9 x 64B fully-used lines per edge).
// Grid 2500 x 256 = 640000 threads == NE exactly -> histogram rides along.
// ---------------------------------------------------------------------------
__global__ __launch_bounds__(256) void node_y(
    const float* __restrict__ x,
    const float* __restrict__ W10,
    const float* __restrict__ W11,
    const float* __restrict__ W12,
    unsigned int* __restrict__ yAll16,
    const int* __restrict__ ei,
    int* __restrict__ counts)
{
    __shared__ float xs[8][288];
    __shared__ float w10[1024];
    __shared__ float w11[1024];
    __shared__ float w12[1024];
    const int tid = threadIdx.x;
    const int nodeBase = blockIdx.x * 8;

    // folded histogram: one edge per thread
    {
        int e = blockIdx.x * 256 + tid;
        atomicAdd(&counts[ei[NE + e]], 1);
    }

    if (tid < 256) {
        ((float4*)w10)[tid] = ((const float4*)W10)[tid];
        ((float4*)w11)[tid] = ((const float4*)W11)[tid];
        ((float4*)w12)[tid] = ((const float4*)W12)[tid];
    }
    for (int i = tid; i < 576; i += 256) {
        int nl = i / 72, q = i % 72;
        int n = nodeBase + nl;
        float4 v = {0.f, 0.f, 0.f, 0.f};
        if (n < NN) v = ((const float4*)(x + (long)n * 288))[q];
        ((float4*)xs[nl])[q] = v;
    }
    __syncthreads();

    const int nl = tid >> 5, v = tid & 31;
    const int n = nodeBase + nl;
    if (n >= NN) return;

    const float inv_mul = 0.17677669529663687f;  // 1/sqrt(32)
    float vals[9];

    {
        float a = 0.f;
        #pragma unroll
        for (int u = 0; u < 32; ++u) a += xs[nl][u] * w10[u * 32 + v];
        vals[0] = a;
    }
    {
        float a0 = 0.f, a1 = 0.f, a2 = 0.f;
        #pragma unroll
        for (int u = 0; u < 32; ++u) {
            float wv = w11[u * 32 + v];
            a0 += xs[nl][32 + u * 3 + 0] * wv;
            a1 += xs[nl][32 + u * 3 + 1] * wv;
            a2 += xs[nl][32 + u * 3 + 2] * wv;
        }
        vals[1] = a0; vals[2] = a1; vals[3] = a2;
    }
    {
        float a[5] = {0.f, 0.f, 0.f, 0.f, 0.f};
        #pragma unroll
        for (int u = 0; u < 32; ++u) {
            float wv = w12[u * 32 + v];
            #pragma unroll
            for (int m = 0; m < 5; ++m) a[m] += xs[nl][128 + u * 5 + m] * wv;
        }
        #pragma unroll
        for (int m = 0; m < 5; ++m) vals[4 + m] = a[m];
    }

    unsigned int* yrow = yAll16 + (long)n * 144;
    const bool evenLane = ((v & 1) == 0);
    #pragma unroll
    for (int pl = 0; pl < 9; ++pl) {
        float mine  = vals[pl] * inv_mul;
        float other = __shfl_xor(mine, 1);
        if (evenLane)
            yrow[pl * 16 + (v >> 1)] = f2bf16(mine) | (f2bf16(other) << 16);
    }
}

// ---------------------------------------------------------------------------
// Kernel A2: sc GEMM. 64 nodes/block; thread = 8 nodes x 3 cols.
// ---------------------------------------------------------------------------
__global__ __launch_bounds__(256) void node_sc(
    const float* __restrict__ x,
    const float* __restrict__ na,
    const float* __restrict__ scW,
    float* __restrict__ sc)
{
    __shared__ float B[128 * 96];
    __shared__ float x0s[64 * 32];
    __shared__ float nas[64 * 4];
    const int tid = threadIdx.x;
    const int nodeBase = blockIdx.x * 64;

    for (int i = tid; i < 3072; i += 256) {
        int qw = i & 7, rest = i >> 3;
        int t = rest & 3, u = (rest >> 2) & 31, h = rest >> 7;
        float4 v = ((const float4*)scW)[i];
        ((float4*)&B[(u * 4 + t) * 96 + h * 32])[qw] = v;
    }
    for (int i = tid; i < 512; i += 256) {
        int nl = i >> 3, q = i & 7;
        int n = nodeBase + nl;
        float4 v = {0.f, 0.f, 0.f, 0.f};
        if (n < NN) v = ((const float4*)(x + (long)n * 288))[q];
        ((float4*)&x0s[nl * 32])[q] = v;
    }
    for (int i = tid; i < 256; i += 256) {
        int nl = i >> 2, t = i & 3;
        int n = nodeBase + nl;
        nas[i] = (n < NN) ? na[n * 4 + t] : 0.f;
    }
    __syncthreads();

    const int g = tid >> 5, c = tid & 31;
    float nav[8][4];
    #pragma unroll
    for (int j = 0; j < 8; ++j)
        #pragma unroll
        for (int t = 0; t < 4; ++t) nav[j][t] = nas[(g * 8 + j) * 4 + t];

    float acc[3][8];
    #pragma unroll
    for (int cc = 0; cc < 3; ++cc)
        #pragma unroll
        for (int j = 0; j < 8; ++j) acc[cc][j] = 0.f;

    for (int u = 0; u < 32; ++u) {
        float aj[8];
        #pragma unroll
        for (int j = 0; j < 8; ++j) aj[j] = x0s[(g * 8 + j) * 32 + u];
        #pragma unroll
        for (int t = 0; t < 4; ++t) {
            float b0 = B[(u * 4 + t) * 96 + c];
            float b1 = B[(u * 4 + t) * 96 + 32 + c];
            float b2 = B[(u * 4 + t) * 96 + 64 + c];
            #pragma unroll
            for (int j = 0; j < 8; ++j) {
                float p = aj[j] * nav[j][t];
                acc[0][j] += p * b0;
                acc[1][j] += p * b1;
                acc[2][j] += p * b2;
            }
        }
    }

    const float inv_sc = 0.08838834764831845f;  // 1/sqrt(128)
    #pragma unroll
    for (int j = 0; j < 8; ++j) {
        int n = nodeBase + g * 8 + j;
        if (n < NN) {
            #pragma unroll
            for (int cc = 0; cc < 3; ++cc)
                sc[((long)cc * NN + n) * 32 + c] = acc[cc][j] * inv_sc;
        }
    }
}

// ---------------------------------------------------------------------------
// scan (block 0) + prep_frags (blocks 1..6) in one launch.
// counts loads vectorized: 5 x int4.
// ---------------------------------------------------------------------------
__global__ __launch_bounds__(1024) void scan_prep(
    const int* __restrict__ counts, int* __restrict__ offsets,
    const float* __restrict__ Wm1, unsigned int* __restrict__ wm1fg)
{
    if (blockIdx.x > 0) {
        int idx = (blockIdx.x - 1) * 1024 + threadIdx.x;   // 0..6143
        int j = idx & 7, lane = (idx >> 3) & 63, sec = idx >> 9;
        int kh = sec / 6, nt = sec % 6;
        int k = kh * 32 + ((lane >> 4) * 8) + j;
        int n = nt * 16 + (lane & 15);
        unsigned int b = f2bf16(Wm1[k * 96 + n] * 0.125f);
        unsigned int other = (unsigned int)__shfl_xor((int)b, 1);
        if ((idx & 1) == 0) wm1fg[idx >> 1] = b | (other << 16);
        return;
    }

    __shared__ int partial[1024];
    const int t = threadIdx.x;
    const int base = t * 20;          // 1024*20 = 20480 >= NN
    int raw[20];
    #pragma unroll
    for (int j = 0; j < 5; ++j) {
        int4 v = ((const int4*)(counts + base))[j];
        raw[j * 4 + 0] = v.x; raw[j * 4 + 1] = v.y;
        raw[j * 4 + 2] = v.z; raw[j * 4 + 3] = v.w;
    }
    int loc[20];
    int s = 0;
    #pragma unroll
    for (int i = 0; i < 20; ++i) {
        int v = (base + i < NN) ? raw[i] : 0;
        loc[i] = s;
        s += v;
    }
    partial[t] = s;
    __syncthreads();
    for (int off = 1; off < 1024; off <<= 1) {
        int v = (t >= off) ? partial[t - off] : 0;
        __syncthreads();
        partial[t] += v;
        __syncthreads();
    }
    int pre = (t == 0) ? 0 : partial[t - 1];
    #pragma unroll
    for (int i = 0; i < 20; ++i)
        if (base + i <= NN) offsets[base + i] = pre + loc[i];
}

// ---------------------------------------------------------------------------
// scatter: ONE int4 (e, s, d, 0) store per edge -> one 64B line touched
// (was 3 scattered stores / 3-4 lines: sidx 4B + ssd 8B + easorted 48B,
// ~160MB effective scattered-write traffic). ea moves back to a gather in
// edge_wg's staging (R1-proven; 36B contiguous per edge, latency-hidden).
// ---------------------------------------------------------------------------
__global__ __launch_bounds__(256) void scatter_ids(
    const int* __restrict__ ei,
    const int* __restrict__ offsets, int* __restrict__ cursor,
    int4* __restrict__ esd)
{
    int e = blockIdx.x * 256 + threadIdx.x;
    if (e < NE) {
        int d = ei[NE + e];
        int s = ei[e];
        int pos = offsets[d] + atomicAdd(&cursor[d], 1);
        esd[pos] = make_int4(e, s, d, 0);
    }
}

// ---------------------------------------------------------------------------
// edge_wg v5 (R12): = R11 (A-frags in registers, 20 KB LDS, 8 blocks/CU,
// v_perm picks) with ea STAGED BY GATHER from the esd ids (easorted array
// eliminated; same values, same order -> bit-identical).
// ---------------------------------------------------------------------------
__global__ __launch_bounds__(256) void edge_wg(
    const float* __restrict__ ee,
    const float* __restrict__ ea,
    const int4*  __restrict__ esd,
    const float* __restrict__ Wm0,
    const unsigned int* __restrict__ wm1fg,
    const unsigned int* __restrict__ yAll16,
    float* __restrict__ mid)
{
    __shared__ float ees[64 * 8];                 // [le*8 + k]    2 KB
    __shared__ float wm0s[512];                   // [k*64 + i]    2 KB
    __shared__ unsigned int wtile[64 * 50];       // D packed   12.5 KB
    __shared__ float easp[64 * 12];               // gathered ea   3 KB
    __shared__ int2 sdsh[64];                     // (src,dst)   0.5 KB

    const int tid = threadIdx.x;
    const long pb = (long)blockIdx.x * 64;        // sorted position base
    const int4* esdp = esd + pb;

    for (int i = tid; i < 512; i += 256) wm0s[i] = Wm0[i];
    for (int i = tid; i < 512; i += 256) {
        int le = i >> 3, k = i & 7;
        int e = esdp[le].x;                       // L1-resident after first
        ees[i] = ee[(long)e * 8 + k];
    }
    for (int i = tid; i < 576; i += 256) {
        int le = i / 9, m = i - le * 9;
        int e = esdp[le].x;
        easp[le * 12 + m] = ea[(long)e * 9 + m];
    }
    if (tid < 64) {
        int4 v = esdp[tid];
        sdsh[tid] = make_int2(v.y, v.z);
    }
    __syncthreads();

    // phase A (merged 1+2): per-lane A-frags in registers, then MFMA.
    {
        const float inv_sqrt8 = 0.35355339059327373f;
        const int wv = tid >> 6, l = tid & 63;
        const int le = wv * 16 + (l & 15);
        const int kb = (l >> 4) * 8;

        float emb[8];
        #pragma unroll
        for (int q = 0; q < 8; ++q) emb[q] = ees[le * 8 + q];

        unsigned int pa0[4], pa1[4];
        #pragma unroll
        for (int i = 0; i < 4; ++i) {
            float h2[2];
            #pragma unroll
            for (int t2 = 0; t2 < 2; ++t2) {
                int k = kb + i * 2 + t2;
                float t = 0.f;
                #pragma unroll
                for (int q = 0; q < 8; ++q) t += emb[q] * wm0s[q * 64 + k];
                h2[t2] = silu_f(t * inv_sqrt8);
            }
            pa0[i] = f2bf16(h2[0]) | (f2bf16(h2[1]) << 16);
        }
        #pragma unroll
        for (int i = 0; i < 4; ++i) {
            float h2[2];
            #pragma unroll
            for (int t2 = 0; t2 < 2; ++t2) {
                int k = 32 + kb + i * 2 + t2;
                float t = 0.f;
                #pragma unroll
                for (int q = 0; q < 8; ++q) t += emb[q] * wm0s[q * 64 + k];
                h2[t2] = silu_f(t * inv_sqrt8);
            }
            pa1[i] = f2bf16(h2[0]) | (f2bf16(h2[1]) << 16);
        }

        uint4v u0 = {pa0[0], pa0[1], pa0[2], pa0[3]};
        uint4v u1 = {pa1[0], pa1[1], pa1[2], pa1[3]};
        const short8v a0f = __builtin_bit_cast(short8v, u0);
        const short8v a1f = __builtin_bit_cast(short8v, u1);

        unsigned short* wts = (unsigned short*)wtile;
        const unsigned short* wm1f = (const unsigned short*)wm1fg;
        const int col = l & 15, rowq = (l >> 4) * 4;
        #pragma unroll
        for (int nt = 0; nt < 6; ++nt) {
            short8v b0 = *(const short8v*)&wm1f[((0 * 6 + nt) * 64 + l) * 8];
            short8v b1 = *(const short8v*)&wm1f[((1 * 6 + nt) * 64 + l) * 8];
            float4v acc = {0.f, 0.f, 0.f, 0.f};
            acc = __builtin_amdgcn_mfma_f32_16x16x32_bf16(a0f, b0, acc, 0, 0, 0);
            acc = __builtin_amdgcn_mfma_f32_16x16x32_bf16(a1f, b1, acc, 0, 0, 0);
            const int c = nt * 16 + col;
            #pragma unroll
            for (int r = 0; r < 4; ++r)
                wts[(wv * 16 + rowq + r) * 100 + c] = (unsigned short)f2bf16(acc[r]);
        }
    }
    __syncthreads();

    // phase 3: consume (R6 structure; picks via v_perm). thread = (channel
    // u, slice sl of 8 sorted edges); run-accumulation, atomic flush.
    {
        const int u = tid & 31, sl = tid >> 5;
        const int p = u >> 1;
        const unsigned int psel = (u & 1) ? 0x03020404u : 0x01000404u;

        const float invAVG = 0.17677669529663687f;                        // 1/sqrt32
        const float c1     = 0.5773502691896258f * 0.17677669529663687f;  // /sqrt3/sqrt32
        const float c2     = 0.4472135954999579f * 0.17677669529663687f;  // /sqrt5/sqrt32

        int curD = -1;
        float a0 = 0.f, a1 = 0.f, a2 = 0.f;
        #pragma unroll
        for (int k = 0; k < 8; ++k) {
            const int le = sl * 8 + k;
            const int2 sd = sdsh[le];
            if (sd.y != curD) {
                if (curD >= 0) {
                    atomicAdd(&mid[(long)curD * 96 + u],      a0 * invAVG);
                    atomicAdd(&mid[(long)curD * 96 + 32 + u], a1 * c1);
                    atomicAdd(&mid[(long)curD * 96 + 64 + u], a2 * c2);
                }
                curD = sd.y; a0 = 0.f; a1 = 0.f; a2 = 0.f;
            }
            const unsigned int* wr = wtile + le * 50;
            const unsigned int* yb = yAll16 + (long)sd.x * 144;
            const float* eav = easp + le * 12;

            float4 ev0 = *(const float4*)&eav[0];
            float4 ev1 = *(const float4*)&eav[4];
            float  ev8 = eav[8];

            float w0 = pickf(wr[p], psel);
            float w1 = pickf(wr[16 + p], psel);
            float w2 = pickf(wr[32 + p], psel);

            a0 += w0 * pickf(yb[p], psel) * ev0.x;

            float d1 = pickf(yb[16 + p], psel) * ev0.y
                     + pickf(yb[32 + p], psel) * ev0.z
                     + pickf(yb[48 + p], psel) * ev0.w;
            a1 += w1 * d1;

            float d2 = pickf(yb[64 + p], psel) * ev1.x
                     + pickf(yb[80 + p], psel) * ev1.y
                     + pickf(yb[96 + p], psel) * ev1.z
                     + pickf(yb[112 + p], psel) * ev1.w
                     + pickf(yb[128 + p], psel) * ev8;
            a2 += w2 * d2;
        }
        if (curD >= 0) {
            atomicAdd(&mid[(long)curD * 96 + u],      a0 * invAVG);
            atomicAdd(&mid[(long)curD * 96 + 32 + u], a1 * c1);
            atomicAdd(&mid[(long)curD * 96 + 64 + u], a2 * c2);
        }
    }
}

// ---------------------------------------------------------------------------
// Kernel C: output GEMV + sc + silu. float4 staging.
// ---------------------------------------------------------------------------
__global__ __launch_bounds__(256) void node_out(
    const float* __restrict__ mid,
    const float* __restrict__ sc,
    const float* __restrict__ L0,
    const float* __restrict__ L1,
    const float* __restrict__ L2,
    float* __restrict__ out)
{
    __shared__ float l0[32 * 32];
    __shared__ float l1[64 * 32];
    __shared__ float l2[96 * 32];
    __shared__ float ms[8][96];
    const int tid = threadIdx.x;
    const int nodeBase = blockIdx.x * 8;

    if (tid < 256) ((float4*)l0)[tid] = ((const float4*)L0)[tid];
    for (int i = tid; i < 512; i += 256) ((float4*)l1)[i] = ((const float4*)L1)[i];
    for (int i = tid; i < 768; i += 256) ((float4*)l2)[i] = ((const float4*)L2)[i];
    for (int i = tid; i < 192; i += 256) {
        int nl = i / 24, q = i % 24;
        int n = nodeBase + nl;
        float4 v = {0.f, 0.f, 0.f, 0.f};
        if (n < NN) v = ((const float4*)(mid + (long)n * 96))[q];
        ((float4*)ms[nl])[q] = v;
    }
    __syncthreads();

    const int nl = tid >> 5, wv = tid & 31;
    const int n = nodeBase + nl;
    if (n >= NN) return;

    float a0 = 0.f, a1 = 0.f, a2 = 0.f;
    #pragma unroll
    for (int u = 0; u < 32; ++u) {
        float m = ms[nl][u];
        a0 += m * l0[u * 32 + wv];
        a1 += m * l1[u * 32 + wv];
        a2 += m * l2[u * 32 + wv];
    }
    #pragma unroll
    for (int u = 32; u < 64; ++u) {
        float m = ms[nl][u];
        a1 += m * l1[u * 32 + wv];
        a2 += m * l2[u * 32 + wv];
    }
    #pragma unroll
    for (int u = 64; u < 96; ++u) a2 += ms[nl][u] * l2[u * 32 + wv];

    const float is32 = 0.17677669529663687f;
    const float is64 = 0.125f;
    const float is96 = 0.10206207261596575f;
    const long base = (long)n * 32 + wv;
    out[base]                     = silu_f(a0 * is32 + sc[base]);
    out[(long)NN * 32 + base]     = silu_f(a1 * is64 + sc[(long)NN * 32 + base]);
    out[(long)2 * NN * 32 + base] = silu_f(a2 * is96 + sc[(long)2 * NN * 32 + base]);
}

extern "C" void kernel_launch(void* const* d_in, const int* in_sizes, int n_in,
                              void* d_out, int out_size, void* d_ws, size_t ws_size,
                              hipStream_t stream)
{
    const float* x   = (const float*)d_in[0];
    const float* na  = (const float*)d_in[1];
    const float* ee  = (const float*)d_in[2];
    const float* ea  = (const float*)d_in[3];
    const int*   ei  = (const int*)d_in[4];
    const float* W10 = (const float*)d_in[5];
    const float* W11 = (const float*)d_in[6];
    const float* W12 = (const float*)d_in[7];
    const float* Wm0 = (const float*)d_in[8];
    const float* Wm1 = (const float*)d_in[9];
    const float* L0  = (const float*)d_in[10];
    const float* L1  = (const float*)d_in[11];
    const float* L2  = (const float*)d_in[12];
    const float* scW = (const float*)d_in[13];
    float* out = (float*)d_out;

    unsigned int* yAll16 = (unsigned int*)d_ws;           // NN*144 uints
    float* sc      = (float*)(yAll16 + (size_t)NN * 144); // 3*NN*32 f32
    int*   counts  = (int*)(sc + (size_t)3 * NN * 32);    // NN  (memset block)
    int*   cursor  = counts + NN;                         // NN  (memset block)
    float* mid     = (float*)(cursor + NN);               // NN*96 (memset block)
    int*   offsets = (int*)(mid + (size_t)NN * 96);       // NN+1 (+3 pad, 16B-mult)
    int4*  esd     = (int4*)(offsets + NN + 4);           // NE int4 (16B-aligned)
    unsigned int* wm1fg = (unsigned int*)(esd + NE);      // 3072

    // zero counts + cursor + mid in one shot (contiguous)
    (void)hipMemsetAsync(counts, 0, (size_t)(2 * NN + NN * 96) * sizeof(int), stream);

    node_y<<<(NN + 7) / 8, 256, 0, stream>>>(x, W10, W11, W12, yAll16, ei, counts);
    scan_prep<<<7, 1024, 0, stream>>>(counts, offsets, Wm1, wm1fg);
    scatter_ids<<<(NE + 255) / 256, 256, 0, stream>>>(ei, offsets, cursor, esd);
    node_sc<<<(NN + 63) / 64, 256, 0, stream>>>(x, na, scW, sc);

    edge_wg<<<NE / 64, 256, 0, stream>>>(ee, ea, esd, Wm0, wm1fg, yAll16, mid);

    node_out<<<(NN + 7) / 8, 256, 0, stream>>>(mid, sc, L0, L1, L2, out);
}

// Round 13
// 326.853 us; speedup vs baseline: 1.5425x; 1.0807x over previous
//
#include <hip/hip_runtime.h>
#include <hip/hip_bf16.h>

#define NN 20000
#define NE 640000

typedef __attribute__((ext_vector_type(8))) short short8v;   // 8 bf16
typedef __attribute__((ext_vector_type(4))) float float4v;
typedef __attribute__((ext_vector_type(4))) unsigned int uint4v;

__device__ __forceinline__ float silu_f(float x) {
    return x / (1.0f + __expf(-x));
}

__device__ __forceinline__ unsigned int f2bf16(float f) {
    __hip_bfloat16 b = __float2bfloat16(f);
    return (unsigned int)*(unsigned short*)&b;
}

// one-instruction bf16-half extraction: v_perm_b32 with per-lane selector.
// sel 0x01000404 -> bytes {v.b1,v.b0,0,0} = v<<16       (lo short, even u)
// sel 0x03020404 -> bytes {v.b3,v.b2,0,0} = v&0xffff0000 (hi short, odd u)
__device__ __forceinline__ float pickf(unsigned int v, unsigned int sel) {
    return __uint_as_float(__builtin_amdgcn_perm(0u, v, sel));
}

// ---------------------------------------------------------------------------
// Kernel A1 (+ edge histogram folded in): per-node y -> packed bf16,
// R0 plane-major layout [n][plane][16] (144 uints) -- line-optimal gather.
// Histogram now STORES THE RANK (atomicAdd return value, previously
// discarded) per edge -> scatter_ids needs no atomics at all.
// Grid 2500 x 256 = 640000 threads == NE exactly.
// ---------------------------------------------------------------------------
__global__ __launch_bounds__(256) void node_y(
    const float* __restrict__ x,
    const float* __restrict__ W10,
    const float* __restrict__ W11,
    const float* __restrict__ W12,
    unsigned int* __restrict__ yAll16,
    const int* __restrict__ ei,
    int* __restrict__ counts,
    int* __restrict__ rank)
{
    __shared__ float xs[8][288];
    __shared__ float w10[1024];
    __shared__ float w11[1024];
    __shared__ float w12[1024];
    const int tid = threadIdx.x;
    const int nodeBase = blockIdx.x * 8;

    // folded histogram: one edge per thread; keep the rank (old count)
    {
        int e = blockIdx.x * 256 + tid;
        rank[e] = atomicAdd(&counts[ei[NE + e]], 1);
    }

    if (tid < 256) {
        ((float4*)w10)[tid] = ((const float4*)W10)[tid];
        ((float4*)w11)[tid] = ((const float4*)W11)[tid];
        ((float4*)w12)[tid] = ((const float4*)W12)[tid];
    }
    for (int i = tid; i < 576; i += 256) {
        int nl = i / 72, q = i % 72;
        int n = nodeBase + nl;
        float4 v = {0.f, 0.f, 0.f, 0.f};
        if (n < NN) v = ((const float4*)(x + (long)n * 288))[q];
        ((float4*)xs[nl])[q] = v;
    }
    __syncthreads();

    const int nl = tid >> 5, v = tid & 31;
    const int n = nodeBase + nl;
    if (n >= NN) return;

    const float inv_mul = 0.17677669529663687f;  // 1/sqrt(32)
    float vals[9];

    {
        float a = 0.f;
        #pragma unroll
        for (int u = 0; u < 32; ++u) a += xs[nl][u] * w10[u * 32 + v];
        vals[0] = a;
    }
    {
        float a0 = 0.f, a1 = 0.f, a2 = 0.f;
        #pragma unroll
        for (int u = 0; u < 32; ++u) {
            float wv = w11[u * 32 + v];
            a0 += xs[nl][32 + u * 3 + 0] * wv;
            a1 += xs[nl][32 + u * 3 + 1] * wv;
            a2 += xs[nl][32 + u * 3 + 2] * wv;
        }
        vals[1] = a0; vals[2] = a1; vals[3] = a2;
    }
    {
        float a[5] = {0.f, 0.f, 0.f, 0.f, 0.f};
        #pragma unroll
        for (int u = 0; u < 32; ++u) {
            float wv = w12[u * 32 + v];
            #pragma unroll
            for (int m = 0; m < 5; ++m) a[m] += xs[nl][128 + u * 5 + m] * wv;
        }
        #pragma unroll
        for (int m = 0; m < 5; ++m) vals[4 + m] = a[m];
    }

    unsigned int* yrow = yAll16 + (long)n * 144;
    const bool evenLane = ((v & 1) == 0);
    #pragma unroll
    for (int pl = 0; pl < 9; ++pl) {
        float mine  = vals[pl] * inv_mul;
        float other = __shfl_xor(mine, 1);
        if (evenLane)
            yrow[pl * 16 + (v >> 1)] = f2bf16(mine) | (f2bf16(other) << 16);
    }
}

// ---------------------------------------------------------------------------
// Kernel A2: sc GEMM. 64 nodes/block; thread = 8 nodes x 3 cols.
// ---------------------------------------------------------------------------
__global__ __launch_bounds__(256) void node_sc(
    const float* __restrict__ x,
    const float* __restrict__ na,
    const float* __restrict__ scW,
    float* __restrict__ sc)
{
    __shared__ float B[128 * 96];
    __shared__ float x0s[64 * 32];
    __shared__ float nas[64 * 4];
    const int tid = threadIdx.x;
    const int nodeBase = blockIdx.x * 64;

    for (int i = tid; i < 3072; i += 256) {
        int qw = i & 7, rest = i >> 3;
        int t = rest & 3, u = (rest >> 2) & 31, h = rest >> 7;
        float4 v = ((const float4*)scW)[i];
        ((float4*)&B[(u * 4 + t) * 96 + h * 32])[qw] = v;
    }
    for (int i = tid; i < 512; i += 256) {
        int nl = i >> 3, q = i & 7;
        int n = nodeBase + nl;
        float4 v = {0.f, 0.f, 0.f, 0.f};
        if (n < NN) v = ((const float4*)(x + (long)n * 288))[q];
        ((float4*)&x0s[nl * 32])[q] = v;
    }
    for (int i = tid; i < 256; i += 256) {
        int nl = i >> 2, t = i & 3;
        int n = nodeBase + nl;
        nas[i] = (n < NN) ? na[n * 4 + t] : 0.f;
    }
    __syncthreads();

    const int g = tid >> 5, c = tid & 31;
    float nav[8][4];
    #pragma unroll
    for (int j = 0; j < 8; ++j)
        #pragma unroll
        for (int t = 0; t < 4; ++t) nav[j][t] = nas[(g * 8 + j) * 4 + t];

    float acc[3][8];
    #pragma unroll
    for (int cc = 0; cc < 3; ++cc)
        #pragma unroll
        for (int j = 0; j < 8; ++j) acc[cc][j] = 0.f;

    for (int u = 0; u < 32; ++u) {
        float aj[8];
        #pragma unroll
        for (int j = 0; j < 8; ++j) aj[j] = x0s[(g * 8 + j) * 32 + u];
        #pragma unroll
        for (int t = 0; t < 4; ++t) {
            float b0 = B[(u * 4 + t) * 96 + c];
            float b1 = B[(u * 4 + t) * 96 + 32 + c];
            float b2 = B[(u * 4 + t) * 96 + 64 + c];
            #pragma unroll
            for (int j = 0; j < 8; ++j) {
                float p = aj[j] * nav[j][t];
                acc[0][j] += p * b0;
                acc[1][j] += p * b1;
                acc[2][j] += p * b2;
            }
        }
    }

    const float inv_sc = 0.08838834764831845f;  // 1/sqrt(128)
    #pragma unroll
    for (int j = 0; j < 8; ++j) {
        int n = nodeBase + g * 8 + j;
        if (n < NN) {
            #pragma unroll
            for (int cc = 0; cc < 3; ++cc)
                sc[((long)cc * NN + n) * 32 + c] = acc[cc][j] * inv_sc;
        }
    }
}

// ---------------------------------------------------------------------------
// scan (block 0) + prep_frags (blocks 1..6) in one launch.
// counts loads vectorized: 5 x int4.
// ---------------------------------------------------------------------------
__global__ __launch_bounds__(1024) void scan_prep(
    const int* __restrict__ counts, int* __restrict__ offsets,
    const float* __restrict__ Wm1, unsigned int* __restrict__ wm1fg)
{
    if (blockIdx.x > 0) {
        int idx = (blockIdx.x - 1) * 1024 + threadIdx.x;   // 0..6143
        int j = idx & 7, lane = (idx >> 3) & 63, sec = idx >> 9;
        int kh = sec / 6, nt = sec % 6;
        int k = kh * 32 + ((lane >> 4) * 8) + j;
        int n = nt * 16 + (lane & 15);
        unsigned int b = f2bf16(Wm1[k * 96 + n] * 0.125f);
        unsigned int other = (unsigned int)__shfl_xor((int)b, 1);
        if ((idx & 1) == 0) wm1fg[idx >> 1] = b | (other << 16);
        return;
    }

    __shared__ int partial[1024];
    const int t = threadIdx.x;
    const int base = t * 20;          // 1024*20 = 20480 >= NN
    int raw[20];
    #pragma unroll
    for (int j = 0; j < 5; ++j) {
        int4 v = ((const int4*)(counts + base))[j];
        raw[j * 4 + 0] = v.x; raw[j * 4 + 1] = v.y;
        raw[j * 4 + 2] = v.z; raw[j * 4 + 3] = v.w;
    }
    int loc[20];
    int s = 0;
    #pragma unroll
    for (int i = 0; i < 20; ++i) {
        int v = (base + i < NN) ? raw[i] : 0;
        loc[i] = s;
        s += v;
    }
    partial[t] = s;
    __syncthreads();
    for (int off = 1; off < 1024; off <<= 1) {
        int v = (t >= off) ? partial[t - off] : 0;
        __syncthreads();
        partial[t] += v;
        __syncthreads();
    }
    int pre = (t == 0) ? 0 : partial[t - 1];
    #pragma unroll
    for (int i = 0; i < 20; ++i)
        if (base + i <= NN) offsets[base + i] = pre + loc[i];
}

// ---------------------------------------------------------------------------
// scatter: ATOMIC-FREE. pos = offsets[d] + rank[e] (rank captured by
// node_y's histogram). Reads coalesced (ei, rank), offsets[d] random 4B
// (80 KB, L2-resident). One int4 (e,s,d,0) store -> one line per edge.
// ---------------------------------------------------------------------------
__global__ __launch_bounds__(256) void scatter_ids(
    const int* __restrict__ ei, const int* __restrict__ rank,
    const int* __restrict__ offsets,
    int4* __restrict__ esd)
{
    int e = blockIdx.x * 256 + threadIdx.x;
    if (e < NE) {
        int d = ei[NE + e];
        int s = ei[e];
        int pos = offsets[d] + rank[e];
        esd[pos] = make_int4(e, s, d, 0);
    }
}

// ---------------------------------------------------------------------------
// edge_wg v5 (R12/R13): A-frags in registers, 20 KB LDS, 8 blocks/CU,
// v_perm picks; ea staged by gather from esd ids.
// ---------------------------------------------------------------------------
__global__ __launch_bounds__(256) void edge_wg(
    const float* __restrict__ ee,
    const float* __restrict__ ea,
    const int4*  __restrict__ esd,
    const float* __restrict__ Wm0,
    const unsigned int* __restrict__ wm1fg,
    const unsigned int* __restrict__ yAll16,
    float* __restrict__ mid)
{
    __shared__ float ees[64 * 8];                 // [le*8 + k]    2 KB
    __shared__ float wm0s[512];                   // [k*64 + i]    2 KB
    __shared__ unsigned int wtile[64 * 50];       // D packed   12.5 KB
    __shared__ float easp[64 * 12];               // gathered ea   3 KB
    __shared__ int2 sdsh[64];                     // (src,dst)   0.5 KB

    const int tid = threadIdx.x;
    const long pb = (long)blockIdx.x * 64;        // sorted position base
    const int4* esdp = esd + pb;

    for (int i = tid; i < 512; i += 256) wm0s[i] = Wm0[i];
    for (int i = tid; i < 512; i += 256) {
        int le = i >> 3, k = i & 7;
        int e = esdp[le].x;                       // L1-resident after first
        ees[i] = ee[(long)e * 8 + k];
    }
    for (int i = tid; i < 576; i += 256) {
        int le = i / 9, m = i - le * 9;
        int e = esdp[le].x;
        easp[le * 12 + m] = ea[(long)e * 9 + m];
    }
    if (tid < 64) {
        int4 v = esdp[tid];
        sdsh[tid] = make_int2(v.y, v.z);
    }
    __syncthreads();

    // phase A (merged 1+2): per-lane A-frags in registers, then MFMA.
    {
        const float inv_sqrt8 = 0.35355339059327373f;
        const int wv = tid >> 6, l = tid & 63;
        const int le = wv * 16 + (l & 15);
        const int kb = (l >> 4) * 8;

        float emb[8];
        #pragma unroll
        for (int q = 0; q < 8; ++q) emb[q] = ees[le * 8 + q];

        unsigned int pa0[4], pa1[4];
        #pragma unroll
        for (int i = 0; i < 4; ++i) {
            float h2[2];
            #pragma unroll
            for (int t2 = 0; t2 < 2; ++t2) {
                int k = kb + i * 2 + t2;
                float t = 0.f;
                #pragma unroll
                for (int q = 0; q < 8; ++q) t += emb[q] * wm0s[q * 64 + k];
                h2[t2] = silu_f(t * inv_sqrt8);
            }
            pa0[i] = f2bf16(h2[0]) | (f2bf16(h2[1]) << 16);
        }
        #pragma unroll
        for (int i = 0; i < 4; ++i) {
            float h2[2];
            #pragma unroll
            for (int t2 = 0; t2 < 2; ++t2) {
                int k = 32 + kb + i * 2 + t2;
                float t = 0.f;
                #pragma unroll
                for (int q = 0; q < 8; ++q) t += emb[q] * wm0s[q * 64 + k];
                h2[t2] = silu_f(t * inv_sqrt8);
            }
            pa1[i] = f2bf16(h2[0]) | (f2bf16(h2[1]) << 16);
        }

        uint4v u0 = {pa0[0], pa0[1], pa0[2], pa0[3]};
        uint4v u1 = {pa1[0], pa1[1], pa1[2], pa1[3]};
        const short8v a0f = __builtin_bit_cast(short8v, u0);
        const short8v a1f = __builtin_bit_cast(short8v, u1);

        unsigned short* wts = (unsigned short*)wtile;
        const unsigned short* wm1f = (const unsigned short*)wm1fg;
        const int col = l & 15, rowq = (l >> 4) * 4;
        #pragma unroll
        for (int nt = 0; nt < 6; ++nt) {
            short8v b0 = *(const short8v*)&wm1f[((0 * 6 + nt) * 64 + l) * 8];
            short8v b1 = *(const short8v*)&wm1f[((1 * 6 + nt) * 64 + l) * 8];
            float4v acc = {0.f, 0.f, 0.f, 0.f};
            acc = __builtin_amdgcn_mfma_f32_16x16x32_bf16(a0f, b0, acc, 0, 0, 0);
            acc = __builtin_amdgcn_mfma_f32_16x16x32_bf16(a1f, b1, acc, 0, 0, 0);
            const int c = nt * 16 + col;
            #pragma unroll
            for (int r = 0; r < 4; ++r)
                wts[(wv * 16 + rowq + r) * 100 + c] = (unsigned short)f2bf16(acc[r]);
        }
    }
    __syncthreads();

    // phase 3: consume (picks via v_perm). thread = (channel u, slice sl
    // of 8 sorted edges); run-accumulation, atomic flush on dest change.
    {
        const int u = tid & 31, sl = tid >> 5;
        const int p = u >> 1;
        const unsigned int psel = (u & 1) ? 0x03020404u : 0x01000404u;

        const float invAVG = 0.17677669529663687f;                        // 1/sqrt32
        const float c1     = 0.5773502691896258f * 0.17677669529663687f;  // /sqrt3/sqrt32
        const float c2     = 0.4472135954999579f * 0.17677669529663687f;  // /sqrt5/sqrt32

        int curD = -1;
        float a0 = 0.f, a1 = 0.f, a2 = 0.f;
        #pragma unroll
        for (int k = 0; k < 8; ++k) {
            const int le = sl * 8 + k;
            const int2 sd = sdsh[le];
            if (sd.y != curD) {
                if (curD >= 0) {
                    atomicAdd(&mid[(long)curD * 96 + u],      a0 * invAVG);
                    atomicAdd(&mid[(long)curD * 96 + 32 + u], a1 * c1);
                    atomicAdd(&mid[(long)curD * 96 + 64 + u], a2 * c2);
                }
                curD = sd.y; a0 = 0.f; a1 = 0.f; a2 = 0.f;
            }
            const unsigned int* wr = wtile + le * 50;
            const unsigned int* yb = yAll16 + (long)sd.x * 144;
            const float* eav = easp + le * 12;

            float4 ev0 = *(const float4*)&eav[0];
            float4 ev1 = *(const float4*)&eav[4];
            float  ev8 = eav[8];

            float w0 = pickf(wr[p], psel);
            float w1 = pickf(wr[16 + p], psel);
            float w2 = pickf(wr[32 + p], psel);

            a0 += w0 * pickf(yb[p], psel) * ev0.x;

            float d1 = pickf(yb[16 + p], psel) * ev0.y
                     + pickf(yb[32 + p], psel) * ev0.z
                     + pickf(yb[48 + p], psel) * ev0.w;
            a1 += w1 * d1;

            float d2 = pickf(yb[64 + p], psel) * ev1.x
                     + pickf(yb[80 + p], psel) * ev1.y
                     + pickf(yb[96 + p], psel) * ev1.z
                     + pickf(yb[112 + p], psel) * ev1.w
                     + pickf(yb[128 + p], psel) * ev8;
            a2 += w2 * d2;
        }
        if (curD >= 0) {
            atomicAdd(&mid[(long)curD * 96 + u],      a0 * invAVG);
            atomicAdd(&mid[(long)curD * 96 + 32 + u], a1 * c1);
            atomicAdd(&mid[(long)curD * 96 + 64 + u], a2 * c2);
        }
    }
}

// ---------------------------------------------------------------------------
// Kernel C: output GEMV + sc + silu. float4 staging.
// ---------------------------------------------------------------------------
__global__ __launch_bounds__(256) void node_out(
    const float* __restrict__ mid,
    const float* __restrict__ sc,
    const float* __restrict__ L0,
    const float* __restrict__ L1,
    const float* __restrict__ L2,
    float* __restrict__ out)
{
    __shared__ float l0[32 * 32];
    __shared__ float l1[64 * 32];
    __shared__ float l2[96 * 32];
    __shared__ float ms[8][96];
    const int tid = threadIdx.x;
    const int nodeBase = blockIdx.x * 8;

    if (tid < 256) ((float4*)l0)[tid] = ((const float4*)L0)[tid];
    for (int i = tid; i < 512; i += 256) ((float4*)l1)[i] = ((const float4*)L1)[i];
    for (int i = tid; i < 768; i += 256) ((float4*)l2)[i] = ((const float4*)L2)[i];
    for (int i = tid; i < 192; i += 256) {
        int nl = i / 24, q = i % 24;
        int n = nodeBase + nl;
        float4 v = {0.f, 0.f, 0.f, 0.f};
        if (n < NN) v = ((const float4*)(mid + (long)n * 96))[q];
        ((float4*)ms[nl])[q] = v;
    }
    __syncthreads();

    const int nl = tid >> 5, wv = tid & 31;
    const int n = nodeBase + nl;
    if (n >= NN) return;

    float a0 = 0.f, a1 = 0.f, a2 = 0.f;
    #pragma unroll
    for (int u = 0; u < 32; ++u) {
        float m = ms[nl][u];
        a0 += m * l0[u * 32 + wv];
        a1 += m * l1[u * 32 + wv];
        a2 += m * l2[u * 32 + wv];
    }
    #pragma unroll
    for (int u = 32; u < 64; ++u) {
        float m = ms[nl][u];
        a1 += m * l1[u * 32 + wv];
        a2 += m * l2[u * 32 + wv];
    }
    #pragma unroll
    for (int u = 64; u < 96; ++u) a2 += ms[nl][u] * l2[u * 32 + wv];

    const float is32 = 0.17677669529663687f;
    const float is64 = 0.125f;
    const float is96 = 0.10206207261596575f;
    const long base = (long)n * 32 + wv;
    out[base]                     = silu_f(a0 * is32 + sc[base]);
    out[(long)NN * 32 + base]     = silu_f(a1 * is64 + sc[(long)NN * 32 + base]);
    out[(long)2 * NN * 32 + base] = silu_f(a2 * is96 + sc[(long)2 * NN * 32 + base]);
}

extern "C" void kernel_launch(void* const* d_in, const int* in_sizes, int n_in,
                              void* d_out, int out_size, void* d_ws, size_t ws_size,
                              hipStream_t stream)
{
    const float* x   = (const float*)d_in[0];
    const float* na  = (const float*)d_in[1];
    const float* ee  = (const float*)d_in[2];
    const float* ea  = (const float*)d_in[3];
    const int*   ei  = (const int*)d_in[4];
    const float* W10 = (const float*)d_in[5];
    const float* W11 = (const float*)d_in[6];
    const float* W12 = (const float*)d_in[7];
    const float* Wm0 = (const float*)d_in[8];
    const float* Wm1 = (const float*)d_in[9];
    const float* L0  = (const float*)d_in[10];
    const float* L1  = (const float*)d_in[11];
    const float* L2  = (const float*)d_in[12];
    const float* scW = (const float*)d_in[13];
    float* out = (float*)d_out;

    unsigned int* yAll16 = (unsigned int*)d_ws;           // NN*144 uints
    float* sc      = (float*)(yAll16 + (size_t)NN * 144); // 3*NN*32 f32
    int*   counts  = (int*)(sc + (size_t)3 * NN * 32);    // NN   (memset block)
    float* mid     = (float*)(counts + NN);               // NN*96 (memset block)
    int*   offsets = (int*)(mid + (size_t)NN * 96);       // NN+1 (+3 pad, 16B-mult)
    int*   rank    = offsets + NN + 4;                    // NE ints
    int4*  esd     = (int4*)(rank + NE);                  // NE int4 (16B-aligned)
    unsigned int* wm1fg = (unsigned int*)(esd + NE);      // 3072

    // zero counts + mid in one shot (contiguous)
    (void)hipMemsetAsync(counts, 0, (size_t)(NN + NN * 96) * sizeof(int), stream);

    node_y<<<(NN + 7) / 8, 256, 0, stream>>>(x, W10, W11, W12, yAll16, ei,
                                             counts, rank);
    scan_prep<<<7, 1024, 0, stream>>>(counts, offsets, Wm1, wm1fg);
    scatter_ids<<<(NE + 255) / 256, 256, 0, stream>>>(ei, rank, offsets, esd);
    node_sc<<<(NN + 63) / 64, 256, 0, stream>>>(x, na, scW, sc);

    edge_wg<<<NE / 64, 256, 0, stream>>>(ee, ea, esd, Wm0, wm1fg, yAll16, mid);

    node_out<<<(NN + 7) / 8, 256, 0, stream>>>(mid, sc, L0, L1, L2, out);
}

// Round 15
// 318.706 us; speedup vs baseline: 1.5819x; 1.0256x over previous
//
#include <hip/hip_runtime.h>
#include <hip/hip_bf16.h>

#define NN 20000
#define NE 640000

typedef __attribute__((ext_vector_type(8))) short short8v;   // 8 bf16
typedef __attribute__((ext_vector_type(4))) float float4v;
typedef __attribute__((ext_vector_type(4))) unsigned int uint4v;

__device__ __forceinline__ float silu_f(float x) {
    return x / (1.0f + __expf(-x));
}

__device__ __forceinline__ unsigned int f2bf16(float f) {
    __hip_bfloat16 b = __float2bfloat16(f);
    return (unsigned int)*(unsigned short*)&b;
}

// one-instruction bf16-half extraction: v_perm_b32 with per-lane selector.
// sel 0x01000404 -> bytes {v.b1,v.b0,0,0} = v<<16       (lo short, even u)
// sel 0x03020404 -> bytes {v.b3,v.b2,0,0} = v&0xffff0000 (hi short, odd u)
__device__ __forceinline__ float pickf(unsigned int v, unsigned int sel) {
    return __uint_as_float(__builtin_amdgcn_perm(0u, v, sel));
}

// ---------------------------------------------------------------------------
// Kernel A1 (+ edge histogram folded in): per-node y -> packed bf16,
// R0 plane-major layout [n][plane][16] (144 uints) -- line-optimal gather.
// Histogram stores the RANK (atomicAdd return) -> scatter needs no atomics.
// Grid 2500 x 256 = 640000 threads == NE exactly.
// ---------------------------------------------------------------------------
__global__ __launch_bounds__(256) void node_y(
    const float* __restrict__ x,
    const float* __restrict__ W10,
    const float* __restrict__ W11,
    const float* __restrict__ W12,
    unsigned int* __restrict__ yAll16,
    const int* __restrict__ ei,
    int* __restrict__ counts,
    int* __restrict__ rank)
{
    __shared__ float xs[8][288];
    __shared__ float w10[1024];
    __shared__ float w11[1024];
    __shared__ float w12[1024];
    const int tid = threadIdx.x;
    const int nodeBase = blockIdx.x * 8;

    // folded histogram: one edge per thread; keep the rank (old count)
    {
        int e = blockIdx.x * 256 + tid;
        rank[e] = atomicAdd(&counts[ei[NE + e]], 1);
    }

    if (tid < 256) {
        ((float4*)w10)[tid] = ((const float4*)W10)[tid];
        ((float4*)w11)[tid] = ((const float4*)W11)[tid];
        ((float4*)w12)[tid] = ((const float4*)W12)[tid];
    }
    for (int i = tid; i < 576; i += 256) {
        int nl = i / 72, q = i % 72;
        int n = nodeBase + nl;
        float4 v = {0.f, 0.f, 0.f, 0.f};
        if (n < NN) v = ((const float4*)(x + (long)n * 288))[q];
        ((float4*)xs[nl])[q] = v;
    }
    __syncthreads();

    const int nl = tid >> 5, v = tid & 31;
    const int n = nodeBase + nl;
    if (n >= NN) return;

    const float inv_mul = 0.17677669529663687f;  // 1/sqrt(32)
    float vals[9];

    {
        float a = 0.f;
        #pragma unroll
        for (int u = 0; u < 32; ++u) a += xs[nl][u] * w10[u * 32 + v];
        vals[0] = a;
    }
    {
        float a0 = 0.f, a1 = 0.f, a2 = 0.f;
        #pragma unroll
        for (int u = 0; u < 32; ++u) {
            float wv = w11[u * 32 + v];
            a0 += xs[nl][32 + u * 3 + 0] * wv;
            a1 += xs[nl][32 + u * 3 + 1] * wv;
            a2 += xs[nl][32 + u * 3 + 2] * wv;
        }
        vals[1] = a0; vals[2] = a1; vals[3] = a2;
    }
    {
        float a[5] = {0.f, 0.f, 0.f, 0.f, 0.f};
        #pragma unroll
        for (int u = 0; u < 32; ++u) {
            float wv = w12[u * 32 + v];
            #pragma unroll
            for (int m = 0; m < 5; ++m) a[m] += xs[nl][128 + u * 5 + m] * wv;
        }
        #pragma unroll
        for (int m = 0; m < 5; ++m) vals[4 + m] = a[m];
    }

    unsigned int* yrow = yAll16 + (long)n * 144;
    const bool evenLane = ((v & 1) == 0);
    #pragma unroll
    for (int pl = 0; pl < 9; ++pl) {
        float mine  = vals[pl] * inv_mul;
        float other = __shfl_xor(mine, 1);
        if (evenLane)
            yrow[pl * 16 + (v >> 1)] = f2bf16(mine) | (f2bf16(other) << 16);
    }
}

// ---------------------------------------------------------------------------
// Kernel A2: sc GEMM. 64 nodes/block; thread = 8 nodes x 3 cols.
// ---------------------------------------------------------------------------
__global__ __launch_bounds__(256) void node_sc(
    const float* __restrict__ x,
    const float* __restrict__ na,
    const float* __restrict__ scW,
    float* __restrict__ sc)
{
    __shared__ float B[128 * 96];
    __shared__ float x0s[64 * 32];
    __shared__ float nas[64 * 4];
    const int tid = threadIdx.x;
    const int nodeBase = blockIdx.x * 64;

    for (int i = tid; i < 3072; i += 256) {
        int qw = i & 7, rest = i >> 3;
        int t = rest & 3, u = (rest >> 2) & 31, h = rest >> 7;
        float4 v = ((const float4*)scW)[i];
        ((float4*)&B[(u * 4 + t) * 96 + h * 32])[qw] = v;
    }
    for (int i = tid; i < 512; i += 256) {
        int nl = i >> 3, q = i & 7;
        int n = nodeBase + nl;
        float4 v = {0.f, 0.f, 0.f, 0.f};
        if (n < NN) v = ((const float4*)(x + (long)n * 288))[q];
        ((float4*)&x0s[nl * 32])[q] = v;
    }
    for (int i = tid; i < 256; i += 256) {
        int nl = i >> 2, t = i & 3;
        int n = nodeBase + nl;
        nas[i] = (n < NN) ? na[n * 4 + t] : 0.f;
    }
    __syncthreads();

    const int g = tid >> 5, c = tid & 31;
    float nav[8][4];
    #pragma unroll
    for (int j = 0; j < 8; ++j)
        #pragma unroll
        for (int t = 0; t < 4; ++t) nav[j][t] = nas[(g * 8 + j) * 4 + t];

    float acc[3][8];
    #pragma unroll
    for (int cc = 0; cc < 3; ++cc)
        #pragma unroll
        for (int j = 0; j < 8; ++j) acc[cc][j] = 0.f;

    for (int u = 0; u < 32; ++u) {
        float aj[8];
        #pragma unroll
        for (int j = 0; j < 8; ++j) aj[j] = x0s[(g * 8 + j) * 32 + u];
        #pragma unroll
        for (int t = 0; t < 4; ++t) {
            float b0 = B[(u * 4 + t) * 96 + c];
            float b1 = B[(u * 4 + t) * 96 + 32 + c];
            float b2 = B[(u * 4 + t) * 96 + 64 + c];
            #pragma unroll
            for (int j = 0; j < 8; ++j) {
                float p = aj[j] * nav[j][t];
                acc[0][j] += p * b0;
                acc[1][j] += p * b1;
                acc[2][j] += p * b2;
            }
        }
    }

    const float inv_sc = 0.08838834764831845f;  // 1/sqrt(128)
    #pragma unroll
    for (int j = 0; j < 8; ++j) {
        int n = nodeBase + g * 8 + j;
        if (n < NN) {
            #pragma unroll
            for (int cc = 0; cc < 3; ++cc)
                sc[((long)cc * NN + n) * 32 + c] = acc[cc][j] * inv_sc;
        }
    }
}

// ---------------------------------------------------------------------------
// scan (block 0) + prep_frags (blocks 1..6) in one launch.
// counts loads vectorized: 5 x int4.
// ---------------------------------------------------------------------------
__global__ __launch_bounds__(1024) void scan_prep(
    const int* __restrict__ counts, int* __restrict__ offsets,
    const float* __restrict__ Wm1, unsigned int* __restrict__ wm1fg)
{
    if (blockIdx.x > 0) {
        int idx = (blockIdx.x - 1) * 1024 + threadIdx.x;   // 0..6143
        int j = idx & 7, lane = (idx >> 3) & 63, sec = idx >> 9;
        int kh = sec / 6, nt = sec % 6;
        int k = kh * 32 + ((lane >> 4) * 8) + j;
        int n = nt * 16 + (lane & 15);
        unsigned int b = f2bf16(Wm1[k * 96 + n] * 0.125f);
        unsigned int other = (unsigned int)__shfl_xor((int)b, 1);
        if ((idx & 1) == 0) wm1fg[idx >> 1] = b | (other << 16);
        return;
    }

    __shared__ int partial[1024];
    const int t = threadIdx.x;
    const int base = t * 20;          // 1024*20 = 20480 >= NN
    int raw[20];
    #pragma unroll
    for (int j = 0; j < 5; ++j) {
        int4 v = ((const int4*)(counts + base))[j];
        raw[j * 4 + 0] = v.x; raw[j * 4 + 1] = v.y;
        raw[j * 4 + 2] = v.z; raw[j * 4 + 3] = v.w;
    }
    int loc[20];
    int s = 0;
    #pragma unroll
    for (int i = 0; i < 20; ++i) {
        int v = (base + i < NN) ? raw[i] : 0;
        loc[i] = s;
        s += v;
    }
    partial[t] = s;
    __syncthreads();
    for (int off = 1; off < 1024; off <<= 1) {
        int v = (t >= off) ? partial[t - off] : 0;
        __syncthreads();
        partial[t] += v;
        __syncthreads();
    }
    int pre = (t == 0) ? 0 : partial[t - 1];
    #pragma unroll
    for (int i = 0; i < 20; ++i)
        if (base + i <= NN) offsets[base + i] = pre + loc[i];
}

// ---------------------------------------------------------------------------
// scatter: ATOMIC-FREE. pos = offsets[d] + rank[e].
// One int4 (e,s,d,0) store -> one line per edge.
// ---------------------------------------------------------------------------
__global__ __launch_bounds__(256) void scatter_ids(
    const int* __restrict__ ei, const int* __restrict__ rank,
    const int* __restrict__ offsets,
    int4* __restrict__ esd)
{
    int e = blockIdx.x * 256 + threadIdx.x;
    if (e < NE) {
        int d = ei[NE + e];
        int s = ei[e];
        int pos = offsets[d] + rank[e];
        esd[pos] = make_int4(e, s, d, 0);
    }
}

// ---------------------------------------------------------------------------
// edge_wg v6 (R14/R15): = R13 (A-frags in registers, 20 KB LDS, 8 blocks/CU,
// v_perm picks, ea gathered) + phase 3 SOFTWARE-PIPELINED 1-deep:
// each iteration issues the NEXT edge's 9 y-loads into NAMED scalar regs
// (no runtime-indexed arrays -> no scratch, R8's trap avoided) before
// consuming the current edge's -> 2 edges of y-gather in flight per thread.
// Accumulation order bit-identical to R13 (only load scheduling moves).
// __launch_bounds__(256,8) pins VGPR <= 64 so 8 blocks/CU is preserved.
// ---------------------------------------------------------------------------
__global__ __launch_bounds__(256, 8) void edge_wg(
    const float* __restrict__ ee,
    const float* __restrict__ ea,
    const int4*  __restrict__ esd,
    const float* __restrict__ Wm0,
    const unsigned int* __restrict__ wm1fg,
    const unsigned int* __restrict__ yAll16,
    float* __restrict__ mid)
{
    __shared__ float ees[64 * 8];                 // [le*8 + k]    2 KB
    __shared__ float wm0s[512];                   // [k*64 + i]    2 KB
    __shared__ unsigned int wtile[64 * 50];       // D packed   12.5 KB
    __shared__ float easp[64 * 12];               // gathered ea   3 KB
    __shared__ int2 sdsh[64];                     // (src,dst)   0.5 KB

    const int tid = threadIdx.x;
    const long pb = (long)blockIdx.x * 64;        // sorted position base
    const int4* esdp = esd + pb;

    for (int i = tid; i < 512; i += 256) wm0s[i] = Wm0[i];
    for (int i = tid; i < 512; i += 256) {
        int le = i >> 3, k = i & 7;
        int e = esdp[le].x;                       // L1-resident after first
        ees[i] = ee[(long)e * 8 + k];
    }
    for (int i = tid; i < 576; i += 256) {
        int le = i / 9, m = i - le * 9;
        int e = esdp[le].x;
        easp[le * 12 + m] = ea[(long)e * 9 + m];
    }
    if (tid < 64) {
        int4 v = esdp[tid];
        sdsh[tid] = make_int2(v.y, v.z);
    }
    __syncthreads();

    // phase A (merged 1+2): per-lane A-frags in registers, then MFMA.
    {
        const float inv_sqrt8 = 0.35355339059327373f;
        const int wv = tid >> 6, l = tid & 63;
        const int le = wv * 16 + (l & 15);
        const int kb = (l >> 4) * 8;

        float emb[8];
        #pragma unroll
        for (int q = 0; q < 8; ++q) emb[q] = ees[le * 8 + q];

        unsigned int pa0[4], pa1[4];
        #pragma unroll
        for (int i = 0; i < 4; ++i) {
            float h2[2];
            #pragma unroll
            for (int t2 = 0; t2 < 2; ++t2) {
                int k = kb + i * 2 + t2;
                float t = 0.f;
                #pragma unroll
                for (int q = 0; q < 8; ++q) t += emb[q] * wm0s[q * 64 + k];
                h2[t2] = silu_f(t * inv_sqrt8);
            }
            pa0[i] = f2bf16(h2[0]) | (f2bf16(h2[1]) << 16);
        }
        #pragma unroll
        for (int i = 0; i < 4; ++i) {
            float h2[2];
            #pragma unroll
            for (int t2 = 0; t2 < 2; ++t2) {
                int k = 32 + kb + i * 2 + t2;
                float t = 0.f;
                #pragma unroll
                for (int q = 0; q < 8; ++q) t += emb[q] * wm0s[q * 64 + k];
                h2[t2] = silu_f(t * inv_sqrt8);
            }
            pa1[i] = f2bf16(h2[0]) | (f2bf16(h2[1]) << 16);
        }

        uint4v u0 = {pa0[0], pa0[1], pa0[2], pa0[3]};
        uint4v u1 = {pa1[0], pa1[1], pa1[2], pa1[3]};
        const short8v a0f = __builtin_bit_cast(short8v, u0);
        const short8v a1f = __builtin_bit_cast(short8v, u1);

        unsigned short* wts = (unsigned short*)wtile;
        const unsigned short* wm1f = (const unsigned short*)wm1fg;
        const int col = l & 15, rowq = (l >> 4) * 4;
        #pragma unroll
        for (int nt = 0; nt < 6; ++nt) {
            short8v b0 = *(const short8v*)&wm1f[((0 * 6 + nt) * 64 + l) * 8];
            short8v b1 = *(const short8v*)&wm1f[((1 * 6 + nt) * 64 + l) * 8];
            float4v acc = {0.f, 0.f, 0.f, 0.f};
            acc = __builtin_amdgcn_mfma_f32_16x16x32_bf16(a0f, b0, acc, 0, 0, 0);
            acc = __builtin_amdgcn_mfma_f32_16x16x32_bf16(a1f, b1, acc, 0, 0, 0);
            const int c = nt * 16 + col;
            #pragma unroll
            for (int r = 0; r < 4; ++r)
                wts[(wv * 16 + rowq + r) * 100 + c] = (unsigned short)f2bf16(acc[r]);
        }
    }
    __syncthreads();

    // phase 3: consume, 1-deep pipelined y-gather (named scalars).
    {
        const int u = tid & 31, sl = tid >> 5;
        const int p = u >> 1;
        const unsigned int psel = (u & 1) ? 0x03020404u : 0x01000404u;

        const float invAVG = 0.17677669529663687f;                        // 1/sqrt32
        const float c1     = 0.5773502691896258f * 0.17677669529663687f;  // /sqrt3/sqrt32
        const float c2     = 0.4472135954999579f * 0.17677669529663687f;  // /sqrt5/sqrt32

        int curD = -1;
        float a0 = 0.f, a1 = 0.f, a2 = 0.f;

        // prologue: prefetch edge 0's y row
        int2 sd = sdsh[sl * 8];
        const unsigned int* ybp = yAll16 + (long)sd.x * 144 + p;
        unsigned int y0 = ybp[0],  y1 = ybp[16],  y2 = ybp[32],
                     y3 = ybp[48], y4 = ybp[64],  y5 = ybp[80],
                     y6 = ybp[96], y7 = ybp[112], y8 = ybp[128];

        #pragma unroll
        for (int k = 0; k < 8; ++k) {
            const int le = sl * 8 + k;

            // issue next edge's independent y loads BEFORE current compute
            int2 sdn = sd;
            unsigned int n0 = y0, n1 = y1, n2 = y2, n3 = y3, n4 = y4,
                         n5 = y5, n6 = y6, n7 = y7, n8 = y8;
            if (k < 7) {
                sdn = sdsh[le + 1];
                const unsigned int* ybn = yAll16 + (long)sdn.x * 144 + p;
                n0 = ybn[0];  n1 = ybn[16];  n2 = ybn[32];
                n3 = ybn[48]; n4 = ybn[64];  n5 = ybn[80];
                n6 = ybn[96]; n7 = ybn[112]; n8 = ybn[128];
            }

            if (sd.y != curD) {
                if (curD >= 0) {
                    atomicAdd(&mid[(long)curD * 96 + u],      a0 * invAVG);
                    atomicAdd(&mid[(long)curD * 96 + 32 + u], a1 * c1);
                    atomicAdd(&mid[(long)curD * 96 + 64 + u], a2 * c2);
                }
                curD = sd.y; a0 = 0.f; a1 = 0.f; a2 = 0.f;
            }

            const unsigned int* wr = wtile + le * 50;
            const float* eav = easp + le * 12;
            float4 ev0 = *(const float4*)&eav[0];
            float4 ev1 = *(const float4*)&eav[4];
            float  ev8 = eav[8];

            float w0 = pickf(wr[p], psel);
            float w1 = pickf(wr[16 + p], psel);
            float w2 = pickf(wr[32 + p], psel);

            a0 += w0 * pickf(y0, psel) * ev0.x;

            float d1 = pickf(y1, psel) * ev0.y
                     + pickf(y2, psel) * ev0.z
                     + pickf(y3, psel) * ev0.w;
            a1 += w1 * d1;

            float d2 = pickf(y4, psel) * ev1.x
                     + pickf(y5, psel) * ev1.y
                     + pickf(y6, psel) * ev1.z
                     + pickf(y7, psel) * ev1.w
                     + pickf(y8, psel) * ev8;
            a2 += w2 * d2;

            sd = sdn;
            y0 = n0; y1 = n1; y2 = n2; y3 = n3; y4 = n4;
            y5 = n5; y6 = n6; y7 = n7; y8 = n8;
        }
        if (curD >= 0) {
            atomicAdd(&mid[(long)curD * 96 + u],      a0 * invAVG);
            atomicAdd(&mid[(long)curD * 96 + 32 + u], a1 * c1);
            atomicAdd(&mid[(long)curD * 96 + 64 + u], a2 * c2);
        }
    }
}

// ---------------------------------------------------------------------------
// Kernel C: output GEMV + sc + silu. float4 staging.
// ---------------------------------------------------------------------------
__global__ __launch_bounds__(256) void node_out(
    const float* __restrict__ mid,
    const float* __restrict__ sc,
    const float* __restrict__ L0,
    const float* __restrict__ L1,
    const float* __restrict__ L2,
    float* __restrict__ out)
{
    __shared__ float l0[32 * 32];
    __shared__ float l1[64 * 32];
    __shared__ float l2[96 * 32];
    __shared__ float ms[8][96];
    const int tid = threadIdx.x;
    const int nodeBase = blockIdx.x * 8;

    if (tid < 256) ((float4*)l0)[tid] = ((const float4*)L0)[tid];
    for (int i = tid; i < 512; i += 256) ((float4*)l1)[i] = ((const float4*)L1)[i];
    for (int i = tid; i < 768; i += 256) ((float4*)l2)[i] = ((const float4*)L2)[i];
    for (int i = tid; i < 192; i += 256) {
        int nl = i / 24, q = i % 24;
        int n = nodeBase + nl;
        float4 v = {0.f, 0.f, 0.f, 0.f};
        if (n < NN) v = ((const float4*)(mid + (long)n * 96))[q];
        ((float4*)ms[nl])[q] = v;
    }
    __syncthreads();

    const int nl = tid >> 5, wv = tid & 31;
    const int n = nodeBase + nl;
    if (n >= NN) return;

    float a0 = 0.f, a1 = 0.f, a2 = 0.f;
    #pragma unroll
    for (int u = 0; u < 32; ++u) {
        float m = ms[nl][u];
        a0 += m * l0[u * 32 + wv];
        a1 += m * l1[u * 32 + wv];
        a2 += m * l2[u * 32 + wv];
    }
    #pragma unroll
    for (int u = 32; u < 64; ++u) {
        float m = ms[nl][u];
        a1 += m * l1[u * 32 + wv];
        a2 += m * l2[u * 32 + wv];
    }
    #pragma unroll
    for (int u = 64; u < 96; ++u) a2 += ms[nl][u] * l2[u * 32 + wv];

    const float is32 = 0.17677669529663687f;
    const float is64 = 0.125f;
    const float is96 = 0.10206207261596575f;
    const long base = (long)n * 32 + wv;
    out[base]                     = silu_f(a0 * is32 + sc[base]);
    out[(long)NN * 32 + base]     = silu_f(a1 * is64 + sc[(long)NN * 32 + base]);
    out[(long)2 * NN * 32 + base] = silu_f(a2 * is96 + sc[(long)2 * NN * 32 + base]);
}

extern "C" void kernel_launch(void* const* d_in, const int* in_sizes, int n_in,
                              void* d_out, int out_size, void* d_ws, size_t ws_size,
                              hipStream_t stream)
{
    const float* x   = (const float*)d_in[0];
    const float* na  = (const float*)d_in[1];
    const float* ee  = (const float*)d_in[2];
    const float* ea  = (const float*)d_in[3];
    const int*   ei  = (const int*)d_in[4];
    const float* W10 = (const float*)d_in[5];
    const float* W11 = (const float*)d_in[6];
    const float* W12 = (const float*)d_in[7];
    const float* Wm0 = (const float*)d_in[8];
    const float* Wm1 = (const float*)d_in[9];
    const float* L0  = (const float*)d_in[10];
    const float* L1  = (const float*)d_in[11];
    const float* L2  = (const float*)d_in[12];
    const float* scW = (const float*)d_in[13];
    float* out = (float*)d_out;

    unsigned int* yAll16 = (unsigned int*)d_ws;           // NN*144 uints
    float* sc      = (float*)(yAll16 + (size_t)NN * 144); // 3*NN*32 f32
    int*   counts  = (int*)(sc + (size_t)3 * NN * 32);    // NN   (memset block)
    float* mid     = (float*)(counts + NN);               // NN*96 (memset block)
    int*   offsets = (int*)(mid + (size_t)NN * 96);       // NN+1 (+3 pad, 16B-mult)
    int*   rank    = offsets + NN + 4;                    // NE ints
    int4*  esd     = (int4*)(rank + NE);                  // NE int4 (16B-aligned)
    unsigned int* wm1fg = (unsigned int*)(esd + NE);      // 3072

    // zero counts + mid in one shot (contiguous)
    (void)hipMemsetAsync(counts, 0, (size_t)(NN + NN * 96) * sizeof(int), stream);

    node_y<<<(NN + 7) / 8, 256, 0, stream>>>(x, W10, W11, W12, yAll16, ei,
                                             counts, rank);
    scan_prep<<<7, 1024, 0, stream>>>(counts, offsets, Wm1, wm1fg);
    scatter_ids<<<(NE + 255) / 256, 256, 0, stream>>>(ei, rank, offsets, esd);
    node_sc<<<(NN + 63) / 64, 256, 0, stream>>>(x, na, scW, sc);

    edge_wg<<<NE / 64, 256, 0, stream>>>(ee, ea, esd, Wm0, wm1fg, yAll16, mid);

    node_out<<<(NN + 7) / 8, 256, 0, stream>>>(mid, sc, L0, L1, L2, out);
}